// Round 2
// baseline (901.820 us; speedup 1.0000x reference)
//
#include <hip/hip_runtime.h>
#include <hip/hip_bf16.h>

typedef __attribute__((ext_vector_type(8))) short short8;
typedef __attribute__((ext_vector_type(4))) float f32x4;
typedef unsigned short u16;

#define S_LEN 2048
#define D_DIM 2048
#define NHEAD 16
#define HDIM 128
#define M_ROWS 4096

#define MFMA(a,b,c) __builtin_amdgcn_mfma_f32_16x16x32_bf16(a,b,c,0,0,0)

__device__ __forceinline__ u16 f2bf(float f) {
  union { float f; unsigned u; } v; v.f = f;
  unsigned r = v.u + 0x7fffu + ((v.u >> 16) & 1u);
  return (u16)(r >> 16);
}

__device__ __forceinline__ void async16(void* lds, const void* g) {
  __builtin_amdgcn_global_load_lds(
      (const __attribute__((address_space(1))) unsigned*)g,
      (__attribute__((address_space(3))) unsigned*)lds, 16, 0, 0);
}

// ---------------- x -> bf16 ----------------
__global__ void k_cvt_x(const float* __restrict__ x, u16* __restrict__ xb) {
  int i = blockIdx.x * 256 + threadIdx.x;
  float4 v = reinterpret_cast<const float4*>(x)[i];
  ushort4 o;
  o.x = f2bf(v.x); o.y = f2bf(v.y); o.z = f2bf(v.z); o.w = f2bf(v.w);
  reinterpret_cast<ushort4*>(xb)[i] = o;
}

// -------- W[k][n] f32 -> Wt[n][k] bf16 (transpose+convert) --------
__global__ void k_cvt_wt(const float* __restrict__ W, u16* __restrict__ Wt) {
  __shared__ u16 tile[32][33];
  int n0 = blockIdx.x * 32, k0 = blockIdx.y * 32;
  int tx = threadIdx.x & 31, ty = threadIdx.x >> 5;
#pragma unroll
  for (int i = 0; i < 4; i++)
    tile[ty + i * 8][tx] = f2bf(W[(size_t)(k0 + ty + i * 8) * D_DIM + n0 + tx]);
  __syncthreads();
#pragma unroll
  for (int i = 0; i < 4; i++)
    Wt[(size_t)(n0 + ty + i * 8) * D_DIM + k0 + tx] = tile[tx][ty + i * 8];
}

// -------- V[b,h,s,d] -> Vt[b,h,d,s] (bf16 transpose) --------
__global__ void k_vtrans(const u16* __restrict__ V, u16* __restrict__ Vt) {
  __shared__ u16 tile[32][33];
  int s0 = blockIdx.x * 32, d0 = blockIdx.y * 32, bh = blockIdx.z;
  const u16* Vp = V + (size_t)bh * S_LEN * HDIM;
  u16* Vtp = Vt + (size_t)bh * HDIM * S_LEN;
  int tx = threadIdx.x & 31, ty = threadIdx.x >> 5;
#pragma unroll
  for (int i = 0; i < 4; i++)
    tile[ty + i * 8][tx] = Vp[(size_t)(s0 + ty + i * 8) * HDIM + d0 + tx];
  __syncthreads();
#pragma unroll
  for (int i = 0; i < 4; i++)
    Vtp[(size_t)(d0 + ty + i * 8) * S_LEN + s0 + tx] = tile[tx][ty + i * 8];
}

// -------- GEMM: C[M][N] = A[M][K] * Bt[N][K]^T, 128x128 tile, 4 waves --------
template <int MODE>
__global__ __launch_bounds__(256) void k_gemm(const u16* __restrict__ A,
                                              const u16* __restrict__ Bt,
                                              void* __restrict__ outp,
                                              const float* __restrict__ fac) {
  __shared__ u16 As[128 * 32];
  __shared__ u16 Bs[128 * 32];
  const int m0 = blockIdx.y * 128, n0 = blockIdx.x * 128;
  const int t = threadIdx.x;
  const int w = t >> 6, l = t & 63;
  const int wr = (w >> 1) * 64, wc = (w & 1) * 64;
  const int lr = l & 15, lk = (l >> 4) * 8;
  f32x4 acc[4][4] = {};

  for (int k0 = 0; k0 < D_DIM; k0 += 32) {
#pragma unroll
    for (int i = 0; i < 2; i++) {
      const int ib = i * 256 + w * 64;
      const int idx = ib + l;
      const int row = idx >> 2, kq = idx & 3;
      async16(As + ib * 8, A + (size_t)(m0 + row) * D_DIM + k0 + kq * 8);
      async16(Bs + ib * 8, Bt + (size_t)(n0 + row) * D_DIM + k0 + kq * 8);
    }
    __syncthreads();
    short8 af[4], bfr[4];
#pragma unroll
    for (int mi = 0; mi < 4; mi++)
      af[mi] = *reinterpret_cast<const short8*>(As + (wr + mi * 16 + lr) * 32 + lk);
#pragma unroll
    for (int ni = 0; ni < 4; ni++)
      bfr[ni] = *reinterpret_cast<const short8*>(Bs + (wc + ni * 16 + lr) * 32 + lk);
#pragma unroll
    for (int mi = 0; mi < 4; mi++)
#pragma unroll
      for (int ni = 0; ni < 4; ni++)
        acc[mi][ni] = MFMA(af[mi], bfr[ni], acc[mi][ni]);
    __syncthreads();
  }

#pragma unroll
  for (int mi = 0; mi < 4; mi++) {
#pragma unroll
    for (int ni = 0; ni < 4; ni++) {
#pragma unroll
      for (int r = 0; r < 4; r++) {
        const int row = m0 + wr + mi * 16 + (l >> 4) * 4 + r;
        const int col = n0 + wc + ni * 16 + lr;
        float v = acc[mi][ni][r];
        if (MODE == 0) {
          ((u16*)outp)[(((size_t)((row >> 11) * NHEAD + (col >> 7))) * S_LEN +
                        (row & 2047)) * HDIM + (col & 127)] = f2bf(v);
        } else {
          ((float*)outp)[(size_t)row * D_DIM + col] = v * (1.0f + 0.1f * fac[row]);
        }
      }
    }
  }
}

// -------- phase projections pq/pk = x @ Wpq / x @ Wpk (f32) --------
__global__ __launch_bounds__(64) void k_phase_proj(const float* __restrict__ x,
                                                   const float* __restrict__ Wpq,
                                                   const float* __restrict__ Wpk,
                                                   float* __restrict__ pq,
                                                   float* __restrict__ pk) {
  int m = blockIdx.x;
  int l = threadIdx.x;
  int h = l & 15, part = l >> 4;
  const float* xr = x + (size_t)m * D_DIM + part * 512;
  float sq = 0.f, sk = 0.f;
  for (int k = 0; k < 512; k++) {
    float xv = xr[k];
    int kk = part * 512 + k;
    sq += xv * Wpq[(size_t)kk * NHEAD + h];
    sk += xv * Wpk[(size_t)kk * NHEAD + h];
  }
  sq += __shfl_xor(sq, 16); sq += __shfl_xor(sq, 32);
  sk += __shfl_xor(sk, 16); sk += __shfl_xor(sk, 32);
  if (l < 16) {
    pq[(size_t)m * NHEAD + l] = sq;
    pk[(size_t)m * NHEAD + l] = sk;
  }
}

__device__ __forceinline__ float wave_sum(float v) {
  v += __shfl_xor(v, 1);  v += __shfl_xor(v, 2);  v += __shfl_xor(v, 4);
  v += __shfl_xor(v, 8);  v += __shfl_xor(v, 16); v += __shfl_xor(v, 32);
  return v;
}

// -------- Ck/Sk = sum_s cos/sin(pk) per (b,h) --------
__global__ void k_phase_ck(const float* __restrict__ pk, float* __restrict__ Ck,
                           float* __restrict__ Sk) {
  int bh = blockIdx.x, b = bh >> 4, h = bh & 15;
  float c = 0.f, s = 0.f;
  for (int ss = threadIdx.x; ss < S_LEN; ss += 256) {
    float v = pk[((size_t)b * S_LEN + ss) * NHEAD + h];
    c += cosf(v); s += sinf(v);
  }
  c = wave_sum(c); s = wave_sum(s);
  __shared__ float rc[4], rs[4];
  int wv = threadIdx.x >> 6;
  if ((threadIdx.x & 63) == 0) { rc[wv] = c; rs[wv] = s; }
  __syncthreads();
  if (threadIdx.x == 0) {
    Ck[bh] = rc[0] + rc[1] + rc[2] + rc[3];
    Sk[bh] = rs[0] + rs[1] + rs[2] + rs[3];
  }
}

// -------- phase_mod[m] --------
__global__ void k_phase_mod(const float* __restrict__ pq, const float* __restrict__ Ck,
                            const float* __restrict__ Sk, float* __restrict__ pm) {
  int m = blockIdx.x * 256 + threadIdx.x;
  int b = m >> 11;
  float a = 0.f;
#pragma unroll
  for (int h = 0; h < NHEAD; h++) {
    float v = pq[(size_t)m * NHEAD + h];
    a += cosf(v) * Ck[b * NHEAD + h] + sinf(v) * Sk[b * NHEAD + h];
  }
  pm[m] = a * (1.0f / (S_LEN * NHEAD));
}

// -------- causal flash attention: 4 waves/block, each wave owns a 16-row q-tile --------
// Block = (qg, bh): waves w=0..3 handle q-tiles qt = qg*4+w. All waves run a
// UNIFORM k-loop bound (last wave's); earlier waves' extra tiles are fully
// masked -> p=0, f=1 no-ops in online softmax, so __syncthreads stays legal.
// P stride padded 32->40 u16 (80B, 16B-aligned) to kill read bank conflicts.
#define PSTR 40
__global__ __launch_bounds__(256) void k_attn(const u16* __restrict__ Q,
                                              const u16* __restrict__ K,
                                              const u16* __restrict__ Vt,
                                              u16* __restrict__ ctx) {
  const int bh = blockIdx.y;
  const int qg = 31 - blockIdx.x;  // longest-first dispatch order
  const int b = bh >> 4, h = bh & 15;
  const int w = threadIdx.x >> 6;
  const int l = threadIdx.x & 63;
  const int qt = qg * 4 + w;
  const int q0 = qt * 16;
  const int lr = l & 15, lg = l >> 4, lk = lg * 8;
  const u16* Qp = Q + (size_t)bh * S_LEN * HDIM;
  const u16* Kp = K + (size_t)bh * S_LEN * HDIM;
  const u16* Vp = Vt + (size_t)bh * HDIM * S_LEN;
  short8 qf[4];
#pragma unroll
  for (int c = 0; c < 4; c++)
    qf[c] = *reinterpret_cast<const short8*>(Qp + (size_t)(q0 + lr) * HDIM + c * 32 + lk);
  f32x4 o[8] = {};
  float mrun[4] = {-1e30f, -1e30f, -1e30f, -1e30f};
  float lrun[4] = {0.f, 0.f, 0.f, 0.f};
  __shared__ __align__(16) u16 P[4][16 * PSTR];
  u16* Pw = &P[w][0];
  const float scale = 0.08838834764831845f;
  const int kend = qg * 64 + 64;  // uniform across the block

  for (int k0 = 0; k0 < kend; k0 += 32) {
    f32x4 s0 = {}, s1 = {};
#pragma unroll
    for (int c = 0; c < 4; c++) {
      short8 kf0 = *reinterpret_cast<const short8*>(Kp + (size_t)(k0 + lr) * HDIM + c * 32 + lk);
      short8 kf1 = *reinterpret_cast<const short8*>(Kp + (size_t)(k0 + 16 + lr) * HDIM + c * 32 + lk);
      s0 = MFMA(qf[c], kf0, s0);
      s1 = MFMA(qf[c], kf1, s1);
    }
    float fres[4];
#pragma unroll
    for (int r = 0; r < 4; r++) {
      const int qq = q0 + lg * 4 + r;
      float v0 = (k0 + lr <= qq) ? s0[r] * scale : -1e30f;
      float v1 = (k0 + 16 + lr <= qq) ? s1[r] * scale : -1e30f;
      float mx = fmaxf(v0, v1);
      mx = fmaxf(mx, __shfl_xor(mx, 1));
      mx = fmaxf(mx, __shfl_xor(mx, 2));
      mx = fmaxf(mx, __shfl_xor(mx, 4));
      mx = fmaxf(mx, __shfl_xor(mx, 8));
      const float nm = fmaxf(mrun[r], mx);
      const float f = __expf(mrun[r] - nm);
      const float p0 = __expf(v0 - nm), p1 = __expf(v1 - nm);
      float rsum = p0 + p1;
      rsum += __shfl_xor(rsum, 1);
      rsum += __shfl_xor(rsum, 2);
      rsum += __shfl_xor(rsum, 4);
      rsum += __shfl_xor(rsum, 8);
      lrun[r] = lrun[r] * f + rsum;
      mrun[r] = nm;
      fres[r] = f;
      Pw[(lg * 4 + r) * PSTR + lr] = f2bf(p0);
      Pw[(lg * 4 + r) * PSTR + 16 + lr] = f2bf(p1);
    }
#pragma unroll
    for (int d = 0; d < 8; d++)
#pragma unroll
      for (int r = 0; r < 4; r++) o[d][r] *= fres[r];
    __syncthreads();
    const short8 pa = *reinterpret_cast<const short8*>(Pw + lr * PSTR + lk);
#pragma unroll
    for (int d = 0; d < 8; d++) {
      short8 vf = *reinterpret_cast<const short8*>(Vp + (size_t)(d * 16 + lr) * S_LEN + k0 + lk);
      o[d] = MFMA(pa, vf, o[d]);
    }
    __syncthreads();
  }

#pragma unroll
  for (int d = 0; d < 8; d++) {
#pragma unroll
    for (int r = 0; r < 4; r++) {
      const int qq = q0 + lg * 4 + r;
      float v = o[d][r] / lrun[r];
      ctx[((size_t)(b * S_LEN + qq)) * D_DIM + h * HDIM + d * 16 + lr] = f2bf(v);
    }
  }
}

extern "C" void kernel_launch(void* const* d_in, const int* in_sizes, int n_in,
                              void* d_out, int out_size, void* d_ws, size_t ws_size,
                              hipStream_t stream) {
  const float* x   = (const float*)d_in[0];
  const float* Wq  = (const float*)d_in[1];
  const float* Wk  = (const float*)d_in[2];
  const float* Wv  = (const float*)d_in[3];
  const float* Wo  = (const float*)d_in[4];
  const float* Wpq = (const float*)d_in[5];
  const float* Wpk = (const float*)d_in[6];

  char* ws = (char*)d_ws;
  u16* xb   = (u16*)(ws + 0);            // 16 MB  x bf16 [4096][2048]
  u16* Wqt  = (u16*)(ws + 16777216);     // 8 MB each, transposed bf16
  u16* Wkt  = (u16*)(ws + 25165824);
  u16* Wvt  = (u16*)(ws + 33554432);
  u16* Wot  = (u16*)(ws + 41943040);
  u16* Qb   = (u16*)(ws + 50331648);     // [b,h,s,d] bf16
  u16* Kb   = (u16*)(ws + 67108864);
  u16* Vb   = (u16*)(ws + 83886080);     // V, later reused as ctx
  u16* Vt   = (u16*)(ws + 100663296);    // [b,h,d,s] bf16
  float* pq = (float*)(ws + 117440512);
  float* pk = (float*)(ws + 117702656);
  float* Ck = (float*)(ws + 117964800);
  float* Sk = (float*)(ws + 117964928);
  float* pm = (float*)(ws + 117965056);

  k_cvt_x<<<dim3(M_ROWS * D_DIM / 1024), 256, 0, stream>>>(x, xb);
  k_cvt_wt<<<dim3(64, 64), 256, 0, stream>>>(Wq, Wqt);
  k_cvt_wt<<<dim3(64, 64), 256, 0, stream>>>(Wk, Wkt);
  k_cvt_wt<<<dim3(64, 64), 256, 0, stream>>>(Wv, Wvt);
  k_cvt_wt<<<dim3(64, 64), 256, 0, stream>>>(Wo, Wot);

  k_gemm<0><<<dim3(16, 32), 256, 0, stream>>>(xb, Wqt, Qb, nullptr);
  k_gemm<0><<<dim3(16, 32), 256, 0, stream>>>(xb, Wkt, Kb, nullptr);
  k_gemm<0><<<dim3(16, 32), 256, 0, stream>>>(xb, Wvt, Vb, nullptr);

  k_vtrans<<<dim3(64, 4, 32), 256, 0, stream>>>(Vb, Vt);

  k_phase_proj<<<dim3(M_ROWS), 64, 0, stream>>>(x, Wpq, Wpk, pq, pk);
  k_phase_ck<<<dim3(32), 256, 0, stream>>>(pk, Ck, Sk);
  k_phase_mod<<<dim3(16), 256, 0, stream>>>(pq, Ck, Sk, pm);

  k_attn<<<dim3(32, 32), 256, 0, stream>>>(Qb, Kb, Vt, Vb /*ctx*/);

  k_gemm<1><<<dim3(16, 32), 256, 0, stream>>>(Vb /*ctx*/, Wot, (void*)d_out, pm);
}

// Round 3
// 696.282 us; speedup vs baseline: 1.2952x; 1.2952x over previous
//
#include <hip/hip_runtime.h>
#include <hip/hip_bf16.h>

typedef __attribute__((ext_vector_type(8))) short short8;
typedef __attribute__((ext_vector_type(4))) float f32x4;
typedef unsigned short u16;

#define S_LEN 2048
#define D_DIM 2048
#define NHEAD 16
#define HDIM 128
#define M_ROWS 4096

#define MFMA(a,b,c) __builtin_amdgcn_mfma_f32_16x16x32_bf16(a,b,c,0,0,0)

__device__ __forceinline__ u16 f2bf(float f) {
  union { float f; unsigned u; } v; v.f = f;
  unsigned r = v.u + 0x7fffu + ((v.u >> 16) & 1u);
  return (u16)(r >> 16);
}

__device__ __forceinline__ void async16(void* lds, const void* g) {
  __builtin_amdgcn_global_load_lds(
      (const __attribute__((address_space(1))) unsigned*)g,
      (__attribute__((address_space(3))) unsigned*)lds, 16, 0, 0);
}

// ---------------- x -> bf16 ----------------
__global__ void k_cvt_x(const float* __restrict__ x, u16* __restrict__ xb) {
  int i = blockIdx.x * 256 + threadIdx.x;
  float4 v = reinterpret_cast<const float4*>(x)[i];
  ushort4 o;
  o.x = f2bf(v.x); o.y = f2bf(v.y); o.z = f2bf(v.z); o.w = f2bf(v.w);
  reinterpret_cast<ushort4*>(xb)[i] = o;
}

// -------- W[k][n] f32 -> Wt[n][k] bf16 (transpose+convert) --------
__global__ void k_cvt_wt(const float* __restrict__ W, u16* __restrict__ Wt) {
  __shared__ u16 tile[32][33];
  int n0 = blockIdx.x * 32, k0 = blockIdx.y * 32;
  int tx = threadIdx.x & 31, ty = threadIdx.x >> 5;
#pragma unroll
  for (int i = 0; i < 4; i++)
    tile[ty + i * 8][tx] = f2bf(W[(size_t)(k0 + ty + i * 8) * D_DIM + n0 + tx]);
  __syncthreads();
#pragma unroll
  for (int i = 0; i < 4; i++)
    Wt[(size_t)(n0 + ty + i * 8) * D_DIM + k0 + tx] = tile[tx][ty + i * 8];
}

// -------- V[b,h,s,d] -> Vt[b,h,d,s] (bf16 transpose) --------
__global__ void k_vtrans(const u16* __restrict__ V, u16* __restrict__ Vt) {
  __shared__ u16 tile[32][33];
  int s0 = blockIdx.x * 32, d0 = blockIdx.y * 32, bh = blockIdx.z;
  const u16* Vp = V + (size_t)bh * S_LEN * HDIM;
  u16* Vtp = Vt + (size_t)bh * HDIM * S_LEN;
  int tx = threadIdx.x & 31, ty = threadIdx.x >> 5;
#pragma unroll
  for (int i = 0; i < 4; i++)
    tile[ty + i * 8][tx] = Vp[(size_t)(s0 + ty + i * 8) * HDIM + d0 + tx];
  __syncthreads();
#pragma unroll
  for (int i = 0; i < 4; i++)
    Vtp[(size_t)(d0 + ty + i * 8) * S_LEN + s0 + tx] = tile[tx][ty + i * 8];
}

// -------- GEMM: C[M][N] = A[M][K] * Bt[N][K]^T, 128x128 tile, 4 waves --------
template <int MODE>
__global__ __launch_bounds__(256) void k_gemm(const u16* __restrict__ A,
                                              const u16* __restrict__ Bt,
                                              void* __restrict__ outp,
                                              const float* __restrict__ fac) {
  __shared__ u16 As[128 * 32];
  __shared__ u16 Bs[128 * 32];
  const int m0 = blockIdx.y * 128, n0 = blockIdx.x * 128;
  const int t = threadIdx.x;
  const int w = t >> 6, l = t & 63;
  const int wr = (w >> 1) * 64, wc = (w & 1) * 64;
  const int lr = l & 15, lk = (l >> 4) * 8;
  f32x4 acc[4][4] = {};

  for (int k0 = 0; k0 < D_DIM; k0 += 32) {
#pragma unroll
    for (int i = 0; i < 2; i++) {
      const int ib = i * 256 + w * 64;
      const int idx = ib + l;
      const int row = idx >> 2, kq = idx & 3;
      async16(As + ib * 8, A + (size_t)(m0 + row) * D_DIM + k0 + kq * 8);
      async16(Bs + ib * 8, Bt + (size_t)(n0 + row) * D_DIM + k0 + kq * 8);
    }
    __syncthreads();
    short8 af[4], bfr[4];
#pragma unroll
    for (int mi = 0; mi < 4; mi++)
      af[mi] = *reinterpret_cast<const short8*>(As + (wr + mi * 16 + lr) * 32 + lk);
#pragma unroll
    for (int ni = 0; ni < 4; ni++)
      bfr[ni] = *reinterpret_cast<const short8*>(Bs + (wc + ni * 16 + lr) * 32 + lk);
#pragma unroll
    for (int mi = 0; mi < 4; mi++)
#pragma unroll
      for (int ni = 0; ni < 4; ni++)
        acc[mi][ni] = MFMA(af[mi], bfr[ni], acc[mi][ni]);
    __syncthreads();
  }

#pragma unroll
  for (int mi = 0; mi < 4; mi++) {
#pragma unroll
    for (int ni = 0; ni < 4; ni++) {
#pragma unroll
      for (int r = 0; r < 4; r++) {
        const int row = m0 + wr + mi * 16 + (l >> 4) * 4 + r;
        const int col = n0 + wc + ni * 16 + lr;
        float v = acc[mi][ni][r];
        if (MODE == 0) {
          ((u16*)outp)[(((size_t)((row >> 11) * NHEAD + (col >> 7))) * S_LEN +
                        (row & 2047)) * HDIM + (col & 127)] = f2bf(v);
        } else {
          ((float*)outp)[(size_t)row * D_DIM + col] = v * (1.0f + 0.1f * fac[row]);
        }
      }
    }
  }
}

// -------- phase projections pq/pk = x @ Wpq / x @ Wpk (f32) --------
__global__ __launch_bounds__(64) void k_phase_proj(const float* __restrict__ x,
                                                   const float* __restrict__ Wpq,
                                                   const float* __restrict__ Wpk,
                                                   float* __restrict__ pq,
                                                   float* __restrict__ pk) {
  int m = blockIdx.x;
  int l = threadIdx.x;
  int h = l & 15, part = l >> 4;
  const float* xr = x + (size_t)m * D_DIM + part * 512;
  float sq = 0.f, sk = 0.f;
  for (int k = 0; k < 512; k++) {
    float xv = xr[k];
    int kk = part * 512 + k;
    sq += xv * Wpq[(size_t)kk * NHEAD + h];
    sk += xv * Wpk[(size_t)kk * NHEAD + h];
  }
  sq += __shfl_xor(sq, 16); sq += __shfl_xor(sq, 32);
  sk += __shfl_xor(sk, 16); sk += __shfl_xor(sk, 32);
  if (l < 16) {
    pq[(size_t)m * NHEAD + l] = sq;
    pk[(size_t)m * NHEAD + l] = sk;
  }
}

__device__ __forceinline__ float wave_sum(float v) {
  v += __shfl_xor(v, 1);  v += __shfl_xor(v, 2);  v += __shfl_xor(v, 4);
  v += __shfl_xor(v, 8);  v += __shfl_xor(v, 16); v += __shfl_xor(v, 32);
  return v;
}

// -------- Ck/Sk = sum_s cos/sin(pk) per (b,h) --------
__global__ void k_phase_ck(const float* __restrict__ pk, float* __restrict__ Ck,
                           float* __restrict__ Sk) {
  int bh = blockIdx.x, b = bh >> 4, h = bh & 15;
  float c = 0.f, s = 0.f;
  for (int ss = threadIdx.x; ss < S_LEN; ss += 256) {
    float v = pk[((size_t)b * S_LEN + ss) * NHEAD + h];
    c += cosf(v); s += sinf(v);
  }
  c = wave_sum(c); s = wave_sum(s);
  __shared__ float rc[4], rs[4];
  int wv = threadIdx.x >> 6;
  if ((threadIdx.x & 63) == 0) { rc[wv] = c; rs[wv] = s; }
  __syncthreads();
  if (threadIdx.x == 0) {
    Ck[bh] = rc[0] + rc[1] + rc[2] + rc[3];
    Sk[bh] = rs[0] + rs[1] + rs[2] + rs[3];
  }
}

// -------- phase_mod[m] --------
__global__ void k_phase_mod(const float* __restrict__ pq, const float* __restrict__ Ck,
                            const float* __restrict__ Sk, float* __restrict__ pm) {
  int m = blockIdx.x * 256 + threadIdx.x;
  int b = m >> 11;
  float a = 0.f;
#pragma unroll
  for (int h = 0; h < NHEAD; h++) {
    float v = pq[(size_t)m * NHEAD + h];
    a += cosf(v) * Ck[b * NHEAD + h] + sinf(v) * Sk[b * NHEAD + h];
  }
  pm[m] = a * (1.0f / (S_LEN * NHEAD));
}

// -------- causal flash attention: 1 wave/block, swapped QK^T, KVBLK=64 --------
// mfma(K,Q) -> C col=lane&15=q-row, row=key: each lane owns ONE q-row, 16
// lane-local scores per 64-key tile. Row max/sum = in-register + 2 shfl_xor.
// P bounced through XOR-swizzled LDS tile ([16][64] bf16, byte^=(row&7)<<4)
// so write (b64) and read (b128) are ~2-way conflict free. f / 1/l bounced
// via 16-float LDS broadcast.
__global__ __launch_bounds__(64) void k_attn(const u16* __restrict__ Q,
                                             const u16* __restrict__ K,
                                             const u16* __restrict__ Vt,
                                             u16* __restrict__ ctx) {
  const int bh = blockIdx.y;
  const int qt = 127 - blockIdx.x;  // longest-first
  const int b = bh >> 4, h = bh & 15;
  const int q0 = qt * 16;
  const int l = threadIdx.x;
  const int lr = l & 15, g = l >> 4, lk = g * 8;
  const u16* Qp = Q + (size_t)bh * S_LEN * HDIM;
  const u16* Kp = K + (size_t)bh * S_LEN * HDIM;
  const u16* Vp = Vt + (size_t)bh * HDIM * S_LEN;
  short8 qf[4];
#pragma unroll
  for (int c = 0; c < 4; c++)
    qf[c] = *reinterpret_cast<const short8*>(Qp + (size_t)(q0 + lr) * HDIM + c * 32 + lk);
  f32x4 o[8] = {};
  float mrun = -1e30f, lsum = 0.f;  // per-lane: q-row = lr
  __shared__ __align__(16) u16 P[16 * 64];
  __shared__ float F[16];
  const float scale = 0.08838834764831845f;
  const int qq = q0 + lr;
  const unsigned swz = (unsigned)((lr & 7) << 4);
  char* Pb = reinterpret_cast<char*>(P);

  for (int k0 = 0; k0 < q0 + 16; k0 += 64) {
    f32x4 s[4] = {};
    __builtin_amdgcn_s_setprio(1);
#pragma unroll
    for (int ks = 0; ks < 4; ks++) {
      const u16* kr = Kp + (size_t)(k0 + ks * 16 + lr) * HDIM + lk;
#pragma unroll
      for (int c = 0; c < 4; c++)
        s[ks] = MFMA(*reinterpret_cast<const short8*>(kr + c * 32), qf[c], s[ks]);
    }
    __builtin_amdgcn_s_setprio(0);
    // ---- lane-local softmax over 16 keys ----
    float p[16];
    float mx = -1e30f;
#pragma unroll
    for (int ks = 0; ks < 4; ks++)
#pragma unroll
      for (int r = 0; r < 4; r++) {
        const int key = k0 + ks * 16 + g * 4 + r;
        const float v = (key <= qq) ? s[ks][r] * scale : -1e30f;
        p[ks * 4 + r] = v;
        mx = fmaxf(mx, v);
      }
    mx = fmaxf(mx, __shfl_xor(mx, 16));
    mx = fmaxf(mx, __shfl_xor(mx, 32));
    const float nm = fmaxf(mrun, mx);
    const float f = __expf(mrun - nm);
    float rs = 0.f;
#pragma unroll
    for (int i = 0; i < 16; i++) { p[i] = __expf(p[i] - nm); rs += p[i]; }
    rs += __shfl_xor(rs, 16);
    rs += __shfl_xor(rs, 32);
    lsum = lsum * f + rs;
    mrun = nm;
    if (l < 16) F[lr] = f;
    // ---- write P (bf16, swizzled) ----
#pragma unroll
    for (int ks = 0; ks < 4; ks++) {
      uint2 pk2;
      pk2.x = (unsigned)f2bf(p[ks * 4 + 0]) | ((unsigned)f2bf(p[ks * 4 + 1]) << 16);
      pk2.y = (unsigned)f2bf(p[ks * 4 + 2]) | ((unsigned)f2bf(p[ks * 4 + 3]) << 16);
      *reinterpret_cast<uint2*>(Pb + (((unsigned)(lr * 128 + ks * 32 + g * 8)) ^ swz)) = pk2;
    }
    __syncthreads();
    const float4 f4 = *reinterpret_cast<const float4*>(&F[g * 4]);
#pragma unroll
    for (int d = 0; d < 8; d++) {
      o[d][0] *= f4.x; o[d][1] *= f4.y; o[d][2] *= f4.z; o[d][3] *= f4.w;
    }
    const short8 pa0 = *reinterpret_cast<const short8*>(Pb + (((unsigned)(lr * 128 + g * 16)) ^ swz));
    const short8 pa1 = *reinterpret_cast<const short8*>(Pb + (((unsigned)(lr * 128 + g * 16 + 64)) ^ swz));
    __builtin_amdgcn_s_setprio(1);
#pragma unroll
    for (int d = 0; d < 8; d++) {
      const u16* vr = Vp + (size_t)(d * 16 + lr) * S_LEN + k0 + lk;
      o[d] = MFMA(pa0, *reinterpret_cast<const short8*>(vr), o[d]);
      o[d] = MFMA(pa1, *reinterpret_cast<const short8*>(vr + 32), o[d]);
    }
    __builtin_amdgcn_s_setprio(0);
    __syncthreads();
  }

  if (l < 16) F[lr] = 1.0f / lsum;
  __syncthreads();
  const float4 rl = *reinterpret_cast<const float4*>(&F[g * 4]);
#pragma unroll
  for (int d = 0; d < 8; d++) {
#pragma unroll
    for (int r = 0; r < 4; r++) {
      const int row = q0 + g * 4 + r;
      const float v = o[d][r] * ((const float*)&rl)[r];
      ctx[((size_t)(b * S_LEN + row)) * D_DIM + h * HDIM + d * 16 + lr] = f2bf(v);
    }
  }
}

extern "C" void kernel_launch(void* const* d_in, const int* in_sizes, int n_in,
                              void* d_out, int out_size, void* d_ws, size_t ws_size,
                              hipStream_t stream) {
  const float* x   = (const float*)d_in[0];
  const float* Wq  = (const float*)d_in[1];
  const float* Wk  = (const float*)d_in[2];
  const float* Wv  = (const float*)d_in[3];
  const float* Wo  = (const float*)d_in[4];
  const float* Wpq = (const float*)d_in[5];
  const float* Wpk = (const float*)d_in[6];

  char* ws = (char*)d_ws;
  u16* xb   = (u16*)(ws + 0);            // 16 MB  x bf16 [4096][2048]
  u16* Wqt  = (u16*)(ws + 16777216);     // 8 MB each, transposed bf16
  u16* Wkt  = (u16*)(ws + 25165824);
  u16* Wvt  = (u16*)(ws + 33554432);
  u16* Wot  = (u16*)(ws + 41943040);
  u16* Qb   = (u16*)(ws + 50331648);     // [b,h,s,d] bf16
  u16* Kb   = (u16*)(ws + 67108864);
  u16* Vb   = (u16*)(ws + 83886080);     // V, later reused as ctx
  u16* Vt   = (u16*)(ws + 100663296);    // [b,h,d,s] bf16
  float* pq = (float*)(ws + 117440512);
  float* pk = (float*)(ws + 117702656);
  float* Ck = (float*)(ws + 117964800);
  float* Sk = (float*)(ws + 117964928);
  float* pm = (float*)(ws + 117965056);

  k_cvt_x<<<dim3(M_ROWS * D_DIM / 1024), 256, 0, stream>>>(x, xb);
  k_cvt_wt<<<dim3(64, 64), 256, 0, stream>>>(Wq, Wqt);
  k_cvt_wt<<<dim3(64, 64), 256, 0, stream>>>(Wk, Wkt);
  k_cvt_wt<<<dim3(64, 64), 256, 0, stream>>>(Wv, Wvt);
  k_cvt_wt<<<dim3(64, 64), 256, 0, stream>>>(Wo, Wot);

  k_gemm<0><<<dim3(16, 32), 256, 0, stream>>>(xb, Wqt, Qb, nullptr);
  k_gemm<0><<<dim3(16, 32), 256, 0, stream>>>(xb, Wkt, Kb, nullptr);
  k_gemm<0><<<dim3(16, 32), 256, 0, stream>>>(xb, Wvt, Vb, nullptr);

  k_vtrans<<<dim3(64, 4, 32), 256, 0, stream>>>(Vb, Vt);

  k_phase_proj<<<dim3(M_ROWS), 64, 0, stream>>>(x, Wpq, Wpk, pq, pk);
  k_phase_ck<<<dim3(32), 256, 0, stream>>>(pk, Ck, Sk);
  k_phase_mod<<<dim3(16), 256, 0, stream>>>(pq, Ck, Sk, pm);

  k_attn<<<dim3(128, 32), 64, 0, stream>>>(Qb, Kb, Vt, Vb /*ctx*/);

  k_gemm<1><<<dim3(16, 32), 256, 0, stream>>>(Vb /*ctx*/, Wot, (void*)d_out, pm);
}

// Round 4
// 367.210 us; speedup vs baseline: 2.4559x; 1.8961x over previous
//
#include <hip/hip_runtime.h>
#include <hip/hip_bf16.h>

typedef __attribute__((ext_vector_type(8))) short short8;
typedef __attribute__((ext_vector_type(4))) float f32x4;
typedef __attribute__((ext_vector_type(16))) float f32x16;
typedef __attribute__((ext_vector_type(4))) int i32x4;
typedef unsigned short u16;

#define S_LEN 2048
#define D_DIM 2048
#define NHEAD 16
#define HDIM 128
#define M_ROWS 4096

#define MFMA(a,b,c) __builtin_amdgcn_mfma_f32_16x16x32_bf16(a,b,c,0,0,0)
#define MFMA32(a,b,c) __builtin_amdgcn_mfma_f32_32x32x16_bf16(a,b,c,0,0,0)

__device__ __forceinline__ u16 f2bf(float f) {
  union { float f; unsigned u; } v; v.f = f;
  unsigned r = v.u + 0x7fffu + ((v.u >> 16) & 1u);
  return (u16)(r >> 16);
}

__device__ __forceinline__ void async16(void* lds, const void* g) {
  __builtin_amdgcn_global_load_lds(
      (const __attribute__((address_space(1))) unsigned*)g,
      (__attribute__((address_space(3))) unsigned*)lds, 16, 0, 0);
}

__device__ __forceinline__ unsigned cvtpk(float lo, float hi) {
  unsigned r;
  asm("v_cvt_pk_bf16_f32 %0, %1, %2" : "=v"(r) : "v"(lo), "v"(hi));
  return r;
}
// v_permlane32_swap_b32: D.lanes[32:63] <-> S.lanes[0:31]
__device__ __forceinline__ void plswap(unsigned& x, unsigned& y) {
  asm("v_permlane32_swap_b32 %0, %1" : "+v"(x), "+v"(y));
}

// ---------------- x -> bf16 ----------------
__global__ void k_cvt_x(const float* __restrict__ x, u16* __restrict__ xb) {
  int i = blockIdx.x * 256 + threadIdx.x;
  float4 v = reinterpret_cast<const float4*>(x)[i];
  ushort4 o;
  o.x = f2bf(v.x); o.y = f2bf(v.y); o.z = f2bf(v.z); o.w = f2bf(v.w);
  reinterpret_cast<ushort4*>(xb)[i] = o;
}

// -------- W[k][n] f32 -> Wt[n][k] bf16 (transpose+convert) --------
__global__ void k_cvt_wt(const float* __restrict__ W, u16* __restrict__ Wt) {
  __shared__ u16 tile[32][33];
  int n0 = blockIdx.x * 32, k0 = blockIdx.y * 32;
  int tx = threadIdx.x & 31, ty = threadIdx.x >> 5;
#pragma unroll
  for (int i = 0; i < 4; i++)
    tile[ty + i * 8][tx] = f2bf(W[(size_t)(k0 + ty + i * 8) * D_DIM + n0 + tx]);
  __syncthreads();
#pragma unroll
  for (int i = 0; i < 4; i++)
    Wt[(size_t)(n0 + ty + i * 8) * D_DIM + k0 + tx] = tile[tx][ty + i * 8];
}

// -------- V[b,h,s,d] -> Vt[b,h,d,s] (bf16 transpose) --------
__global__ void k_vtrans(const u16* __restrict__ V, u16* __restrict__ Vt) {
  __shared__ u16 tile[32][33];
  int s0 = blockIdx.x * 32, d0 = blockIdx.y * 32, bh = blockIdx.z;
  const u16* Vp = V + (size_t)bh * S_LEN * HDIM;
  u16* Vtp = Vt + (size_t)bh * HDIM * S_LEN;
  int tx = threadIdx.x & 31, ty = threadIdx.x >> 5;
#pragma unroll
  for (int i = 0; i < 4; i++)
    tile[ty + i * 8][tx] = Vp[(size_t)(s0 + ty + i * 8) * HDIM + d0 + tx];
  __syncthreads();
#pragma unroll
  for (int i = 0; i < 4; i++)
    Vtp[(size_t)(d0 + ty + i * 8) * S_LEN + s0 + tx] = tile[tx][ty + i * 8];
}

// -------- GEMM: C[M][N] = A[M][K] * Bt[N][K]^T, 128x128 tile, 4 waves --------
template <int MODE>
__global__ __launch_bounds__(256) void k_gemm(const u16* __restrict__ A,
                                              const u16* __restrict__ Bt,
                                              void* __restrict__ outp,
                                              const float* __restrict__ fac) {
  __shared__ u16 As[128 * 32];
  __shared__ u16 Bs[128 * 32];
  const int m0 = blockIdx.y * 128, n0 = blockIdx.x * 128;
  const int t = threadIdx.x;
  const int w = t >> 6, l = t & 63;
  const int wr = (w >> 1) * 64, wc = (w & 1) * 64;
  const int lr = l & 15, lk = (l >> 4) * 8;
  f32x4 acc[4][4] = {};

  for (int k0 = 0; k0 < D_DIM; k0 += 32) {
#pragma unroll
    for (int i = 0; i < 2; i++) {
      const int ib = i * 256 + w * 64;
      const int idx = ib + l;
      const int row = idx >> 2, kq = idx & 3;
      async16(As + ib * 8, A + (size_t)(m0 + row) * D_DIM + k0 + kq * 8);
      async16(Bs + ib * 8, Bt + (size_t)(n0 + row) * D_DIM + k0 + kq * 8);
    }
    __syncthreads();
    short8 af[4], bfr[4];
#pragma unroll
    for (int mi = 0; mi < 4; mi++)
      af[mi] = *reinterpret_cast<const short8*>(As + (wr + mi * 16 + lr) * 32 + lk);
#pragma unroll
    for (int ni = 0; ni < 4; ni++)
      bfr[ni] = *reinterpret_cast<const short8*>(Bs + (wc + ni * 16 + lr) * 32 + lk);
#pragma unroll
    for (int mi = 0; mi < 4; mi++)
#pragma unroll
      for (int ni = 0; ni < 4; ni++)
        acc[mi][ni] = MFMA(af[mi], bfr[ni], acc[mi][ni]);
    __syncthreads();
  }

#pragma unroll
  for (int mi = 0; mi < 4; mi++) {
#pragma unroll
    for (int ni = 0; ni < 4; ni++) {
#pragma unroll
      for (int r = 0; r < 4; r++) {
        const int row = m0 + wr + mi * 16 + (l >> 4) * 4 + r;
        const int col = n0 + wc + ni * 16 + lr;
        float v = acc[mi][ni][r];
        if (MODE == 0) {
          ((u16*)outp)[(((size_t)((row >> 11) * NHEAD + (col >> 7))) * S_LEN +
                        (row & 2047)) * HDIM + (col & 127)] = f2bf(v);
        } else {
          ((float*)outp)[(size_t)row * D_DIM + col] = v * (1.0f + 0.1f * fac[row]);
        }
      }
    }
  }
}

// -------- phase projections pq/pk = x @ Wpq / x @ Wpk (f32) --------
__global__ __launch_bounds__(64) void k_phase_proj(const float* __restrict__ x,
                                                   const float* __restrict__ Wpq,
                                                   const float* __restrict__ Wpk,
                                                   float* __restrict__ pq,
                                                   float* __restrict__ pk) {
  int m = blockIdx.x;
  int l = threadIdx.x;
  int h = l & 15, part = l >> 4;
  const float* xr = x + (size_t)m * D_DIM + part * 512;
  float sq = 0.f, sk = 0.f;
  for (int k = 0; k < 512; k++) {
    float xv = xr[k];
    int kk = part * 512 + k;
    sq += xv * Wpq[(size_t)kk * NHEAD + h];
    sk += xv * Wpk[(size_t)kk * NHEAD + h];
  }
  sq += __shfl_xor(sq, 16); sq += __shfl_xor(sq, 32);
  sk += __shfl_xor(sk, 16); sk += __shfl_xor(sk, 32);
  if (l < 16) {
    pq[(size_t)m * NHEAD + l] = sq;
    pk[(size_t)m * NHEAD + l] = sk;
  }
}

__device__ __forceinline__ float wave_sum(float v) {
  v += __shfl_xor(v, 1);  v += __shfl_xor(v, 2);  v += __shfl_xor(v, 4);
  v += __shfl_xor(v, 8);  v += __shfl_xor(v, 16); v += __shfl_xor(v, 32);
  return v;
}

// -------- Ck/Sk = sum_s cos/sin(pk) per (b,h) --------
__global__ void k_phase_ck(const float* __restrict__ pk, float* __restrict__ Ck,
                           float* __restrict__ Sk) {
  int bh = blockIdx.x, b = bh >> 4, h = bh & 15;
  float c = 0.f, s = 0.f;
  for (int ss = threadIdx.x; ss < S_LEN; ss += 256) {
    float v = pk[((size_t)b * S_LEN + ss) * NHEAD + h];
    c += cosf(v); s += sinf(v);
  }
  c = wave_sum(c); s = wave_sum(s);
  __shared__ float rc[4], rs[4];
  int wv = threadIdx.x >> 6;
  if ((threadIdx.x & 63) == 0) { rc[wv] = c; rs[wv] = s; }
  __syncthreads();
  if (threadIdx.x == 0) {
    Ck[bh] = rc[0] + rc[1] + rc[2] + rc[3];
    Sk[bh] = rs[0] + rs[1] + rs[2] + rs[3];
  }
}

// -------- phase_mod[m] --------
__global__ void k_phase_mod(const float* __restrict__ pq, const float* __restrict__ Ck,
                            const float* __restrict__ Sk, float* __restrict__ pm) {
  int m = blockIdx.x * 256 + threadIdx.x;
  int b = m >> 11;
  float a = 0.f;
#pragma unroll
  for (int h = 0; h < NHEAD; h++) {
    float v = pq[(size_t)m * NHEAD + h];
    a += cosf(v) * Ck[b * NHEAD + h] + sinf(v) * Sk[b * NHEAD + h];
  }
  pm[m] = a * (1.0f / (S_LEN * NHEAD));
}

// -------- causal flash attention: 4 warps x 32 q-rows, LDS-staged K/V --------
// Swapped 32x32x16 MFMA: S[key][q], lane owns q = l&31, 16 regs = keys
// (r&3)+8*(r>>2)+4*hi. K/V staged via global_load_lds (linear dest) with
// PRE-SWIZZLED global source (byte ^= (row&7)<<4 within row); ds_read applies
// the same XOR -> conflict-free strided fragment reads. P->B-frag via
// v_cvt_pk_bf16_f32 + v_permlane32_swap_b32 (in-register, no LDS bounce).
__global__ __launch_bounds__(256, 2) void k_attn(const u16* __restrict__ Q,
                                                 const u16* __restrict__ K,
                                                 const u16* __restrict__ Vt,
                                                 u16* __restrict__ ctx) {
  const int bh = blockIdx.x;
  const int gy = blockIdx.y;
  const int g = (gy < 8) ? (15 - gy) : (gy - 8);  // pair long/short across dispatch
  const int b = bh >> 4, h = bh & 15;
  const int t = threadIdx.x;
  const int w = t >> 6, l = t & 63;
  const int ln = l & 31, hi = l >> 5;
  const int q0w = g * 128 + w * 32;
  const int qq = q0w + ln;
  const float scale = 0.08838834764831845f;

  const u16* Qp = Q + (size_t)bh * S_LEN * HDIM;
  const char* Kg = (const char*)(K + (size_t)bh * S_LEN * HDIM);
  const char* Vg = (const char*)(Vt + (size_t)bh * HDIM * S_LEN);

  __shared__ __align__(16) char Ks[16384];  // [64 keys][128 dims] bf16, data XOR-swizzled
  __shared__ __align__(16) char Vs[16384];  // [128 dims][64 keys] bf16, data XOR-swizzled

  // Q fragment: 8 dim-slices of 16, B-operand layout (col=q, k=hi*8+j)
  short8 qf[8];
#pragma unroll
  for (int c = 0; c < 8; c++)
    qf[c] = *reinterpret_cast<const short8*>(Qp + (size_t)qq * HDIM + c * 16 + hi * 8);

  f32x16 o[4];
#pragma unroll
  for (int ds = 0; ds < 4; ds++)
#pragma unroll
    for (int r = 0; r < 16; r++) o[ds][r] = 0.f;
  float mrun = -1e30f, lsum = 0.f;

  const int kend = (g + 1) * 128;
  for (int k0 = 0; k0 < kend; k0 += 64) {
    // ---- stage K (16KB) + V (16KB), pre-swizzled source, linear LDS dest ----
#pragma unroll
    for (int i = 0; i < 4; i++) {
      const int key = i * 16 + w * 4 + (l >> 4);
      async16(Ks + i * 4096 + w * 1024,
              Kg + (size_t)(k0 + key) * 256 + (((l & 15) * 16) ^ ((key & 7) << 4)));
      const int d = i * 32 + w * 8 + (l >> 3);
      async16(Vs + i * 4096 + w * 1024,
              Vg + (size_t)d * (S_LEN * 2) + k0 * 2 + (((l & 7) * 16) ^ ((d & 7) << 4)));
    }
    __syncthreads();
    if (k0 < q0w + 32) {  // warp-uniform: tile has unmasked keys for this warp
      // ---- QK^T (swapped): S[key][q] ----
      f32x16 s[2];
#pragma unroll
      for (int ks = 0; ks < 2; ks++)
#pragma unroll
        for (int r = 0; r < 16; r++) s[ks][r] = 0.f;
      __builtin_amdgcn_s_setprio(1);
#pragma unroll
      for (int ks = 0; ks < 2; ks++) {
        const int key = ks * 32 + ln;
        const char* kb = Ks + key * 256;
        const unsigned swzk = (unsigned)((key & 7) << 4);
#pragma unroll
        for (int c = 0; c < 8; c++) {
          const short8 kf = *reinterpret_cast<const short8*>(
              kb + (((unsigned)(c * 32 + hi * 16)) ^ swzk));
          s[ks] = MFMA32(kf, qf[c], s[ks]);
        }
      }
      __builtin_amdgcn_s_setprio(0);
      // ---- online softmax, lane-local over 32 of 64 keys ----
      float p[32];
      float mx = -1e30f;
#pragma unroll
      for (int ks = 0; ks < 2; ks++)
#pragma unroll
        for (int r = 0; r < 16; r++) {
          const int key = k0 + ks * 32 + (r & 3) + 8 * (r >> 2) + 4 * hi;
          const float v = (key <= qq) ? s[ks][r] * scale : -1e30f;
          p[ks * 16 + r] = v;
          mx = fmaxf(mx, v);
        }
      mx = fmaxf(mx, __shfl_xor(mx, 32));
      const float nm = fmaxf(mrun, mx);
      const float f = __expf(mrun - nm);
      float rs = 0.f;
#pragma unroll
      for (int i = 0; i < 32; i++) { p[i] = __expf(p[i] - nm); rs += p[i]; }
      rs += __shfl_xor(rs, 32);
      lsum = lsum * f + rs;
      mrun = nm;
#pragma unroll
      for (int ds = 0; ds < 4; ds++)
#pragma unroll
        for (int r = 0; r < 16; r++) o[ds][r] *= f;
      // ---- build PV B-frags in-register (cvt_pk + permlane32_swap) ----
      short8 bfr[4];
#pragma unroll
      for (int sub = 0; sub < 2; sub++) {
#pragma unroll
        for (int half = 0; half < 2; half++) {
          const int pb = sub * 16 + half * 8;
          unsigned X1 = cvtpk(p[pb + 0], p[pb + 1]);
          unsigned X2 = cvtpk(p[pb + 2], p[pb + 3]);
          unsigned Y1 = cvtpk(p[pb + 4], p[pb + 5]);
          unsigned Y2 = cvtpk(p[pb + 6], p[pb + 7]);
          plswap(X1, Y1);
          plswap(X2, Y2);
          i32x4 bw;
          bw[0] = (int)X1; bw[1] = (int)X2; bw[2] = (int)Y1; bw[3] = (int)Y2;
          bfr[sub * 2 + half] = __builtin_bit_cast(short8, bw);
        }
      }
      // ---- PV: O[d][q] += V^T[d][k] * P[k][q] ----
      __builtin_amdgcn_s_setprio(1);
#pragma unroll
      for (int ds = 0; ds < 4; ds++) {
        const int d = ds * 32 + ln;
        const char* vb = Vs + d * 128;
        const unsigned swzv = (unsigned)((d & 7) << 4);
#pragma unroll
        for (int slot = 0; slot < 4; slot++) {
          const short8 vf = *reinterpret_cast<const short8*>(
              vb + (((unsigned)(slot * 32 + hi * 16)) ^ swzv));
          o[ds] = MFMA32(vf, bfr[slot], o[ds]);
        }
      }
      __builtin_amdgcn_s_setprio(0);
    }
    __syncthreads();
  }

  const float rl = 1.0f / lsum;
#pragma unroll
  for (int ds = 0; ds < 4; ds++) {
#pragma unroll
    for (int rq = 0; rq < 4; rq++) {
      const int d = ds * 32 + 8 * rq + 4 * hi;
      ushort4 pk4;
      pk4.x = f2bf(o[ds][rq * 4 + 0] * rl);
      pk4.y = f2bf(o[ds][rq * 4 + 1] * rl);
      pk4.z = f2bf(o[ds][rq * 4 + 2] * rl);
      pk4.w = f2bf(o[ds][rq * 4 + 3] * rl);
      *reinterpret_cast<ushort4*>(ctx + ((size_t)(b * S_LEN + qq)) * D_DIM + h * HDIM + d) = pk4;
    }
  }
}

extern "C" void kernel_launch(void* const* d_in, const int* in_sizes, int n_in,
                              void* d_out, int out_size, void* d_ws, size_t ws_size,
                              hipStream_t stream) {
  const float* x   = (const float*)d_in[0];
  const float* Wq  = (const float*)d_in[1];
  const float* Wk  = (const float*)d_in[2];
  const float* Wv  = (const float*)d_in[3];
  const float* Wo  = (const float*)d_in[4];
  const float* Wpq = (const float*)d_in[5];
  const float* Wpk = (const float*)d_in[6];

  char* ws = (char*)d_ws;
  u16* xb   = (u16*)(ws + 0);            // 16 MB  x bf16 [4096][2048]
  u16* Wqt  = (u16*)(ws + 16777216);     // 8 MB each, transposed bf16
  u16* Wkt  = (u16*)(ws + 25165824);
  u16* Wvt  = (u16*)(ws + 33554432);
  u16* Wot  = (u16*)(ws + 41943040);
  u16* Qb   = (u16*)(ws + 50331648);     // [b,h,s,d] bf16
  u16* Kb   = (u16*)(ws + 67108864);
  u16* Vb   = (u16*)(ws + 83886080);     // V, later reused as ctx
  u16* Vt   = (u16*)(ws + 100663296);    // [b,h,d,s] bf16
  float* pq = (float*)(ws + 117440512);
  float* pk = (float*)(ws + 117702656);
  float* Ck = (float*)(ws + 117964800);
  float* Sk = (float*)(ws + 117964928);
  float* pm = (float*)(ws + 117965056);

  k_cvt_x<<<dim3(M_ROWS * D_DIM / 1024), 256, 0, stream>>>(x, xb);
  k_cvt_wt<<<dim3(64, 64), 256, 0, stream>>>(Wq, Wqt);
  k_cvt_wt<<<dim3(64, 64), 256, 0, stream>>>(Wk, Wkt);
  k_cvt_wt<<<dim3(64, 64), 256, 0, stream>>>(Wv, Wvt);
  k_cvt_wt<<<dim3(64, 64), 256, 0, stream>>>(Wo, Wot);

  k_gemm<0><<<dim3(16, 32), 256, 0, stream>>>(xb, Wqt, Qb, nullptr);
  k_gemm<0><<<dim3(16, 32), 256, 0, stream>>>(xb, Wkt, Kb, nullptr);
  k_gemm<0><<<dim3(16, 32), 256, 0, stream>>>(xb, Wvt, Vb, nullptr);

  k_vtrans<<<dim3(64, 4, 32), 256, 0, stream>>>(Vb, Vt);

  k_phase_proj<<<dim3(M_ROWS), 64, 0, stream>>>(x, Wpq, Wpk, pq, pk);
  k_phase_ck<<<dim3(32), 256, 0, stream>>>(pk, Ck, Sk);
  k_phase_mod<<<dim3(16), 256, 0, stream>>>(pq, Ck, Sk, pm);

  k_attn<<<dim3(32, 16), 256, 0, stream>>>(Qb, Kb, Vt, Vb /*ctx*/);

  k_gemm<1><<<dim3(16, 32), 256, 0, stream>>>(Vb /*ctx*/, Wot, (void*)d_out, pm);
}

// Round 5
// 350.852 us; speedup vs baseline: 2.5704x; 1.0466x over previous
//
#include <hip/hip_runtime.h>
#include <hip/hip_bf16.h>

typedef __attribute__((ext_vector_type(8))) short short8;
typedef __attribute__((ext_vector_type(4))) float f32x4;
typedef __attribute__((ext_vector_type(16))) float f32x16;
typedef __attribute__((ext_vector_type(4))) int i32x4;
typedef unsigned short u16;

#define S_LEN 2048
#define D_DIM 2048
#define NHEAD 16
#define HDIM 128
#define M_ROWS 4096

#define MFMA(a,b,c) __builtin_amdgcn_mfma_f32_16x16x32_bf16(a,b,c,0,0,0)
#define MFMA32(a,b,c) __builtin_amdgcn_mfma_f32_32x32x16_bf16(a,b,c,0,0,0)

__device__ __forceinline__ u16 f2bf(float f) {
  union { float f; unsigned u; } v; v.f = f;
  unsigned r = v.u + 0x7fffu + ((v.u >> 16) & 1u);
  return (u16)(r >> 16);
}

__device__ __forceinline__ void async16(void* lds, const void* g) {
  __builtin_amdgcn_global_load_lds(
      (const __attribute__((address_space(1))) unsigned*)g,
      (__attribute__((address_space(3))) unsigned*)lds, 16, 0, 0);
}

__device__ __forceinline__ unsigned cvtpk(float lo, float hi) {
  unsigned r;
  asm("v_cvt_pk_bf16_f32 %0, %1, %2" : "=v"(r) : "v"(lo), "v"(hi));
  return r;
}
__device__ __forceinline__ void plswap(unsigned& x, unsigned& y) {
  asm("v_permlane32_swap_b32 %0, %1" : "+v"(x), "+v"(y));
}

// ---------------- x -> bf16 ----------------
__global__ void k_cvt_x(const float* __restrict__ x, u16* __restrict__ xb) {
  int i = blockIdx.x * 256 + threadIdx.x;
  float4 v = reinterpret_cast<const float4*>(x)[i];
  ushort4 o;
  o.x = f2bf(v.x); o.y = f2bf(v.y); o.z = f2bf(v.z); o.w = f2bf(v.w);
  reinterpret_cast<ushort4*>(xb)[i] = o;
}

// -------- W[k][n] f32 -> Wt[n][k] bf16 (transpose+convert) --------
__global__ void k_cvt_wt(const float* __restrict__ W, u16* __restrict__ Wt) {
  __shared__ u16 tile[32][33];
  int n0 = blockIdx.x * 32, k0 = blockIdx.y * 32;
  int tx = threadIdx.x & 31, ty = threadIdx.x >> 5;
#pragma unroll
  for (int i = 0; i < 4; i++)
    tile[ty + i * 8][tx] = f2bf(W[(size_t)(k0 + ty + i * 8) * D_DIM + n0 + tx]);
  __syncthreads();
#pragma unroll
  for (int i = 0; i < 4; i++)
    Wt[(size_t)(n0 + ty + i * 8) * D_DIM + k0 + tx] = tile[tx][ty + i * 8];
}

// -------- V[b,h,s,d] -> Vt[b,h,d,s] (bf16 transpose) --------
__global__ void k_vtrans(const u16* __restrict__ V, u16* __restrict__ Vt) {
  __shared__ u16 tile[32][33];
  int s0 = blockIdx.x * 32, d0 = blockIdx.y * 32, bh = blockIdx.z;
  const u16* Vp = V + (size_t)bh * S_LEN * HDIM;
  u16* Vtp = Vt + (size_t)bh * HDIM * S_LEN;
  int tx = threadIdx.x & 31, ty = threadIdx.x >> 5;
#pragma unroll
  for (int i = 0; i < 4; i++)
    tile[ty + i * 8][tx] = Vp[(size_t)(s0 + ty + i * 8) * HDIM + d0 + tx];
  __syncthreads();
#pragma unroll
  for (int i = 0; i < 4; i++)
    Vtp[(size_t)(d0 + ty + i * 8) * S_LEN + s0 + tx] = tile[tx][ty + i * 8];
}

// ======== 256x256-tile 8-phase GEMM: C = A[M][K] * Bt[N][K]^T ========
// BK=64, 8 waves (2Mx4N), per-wave 128x64 output (acc[8][4] f32x4).
// LDS 128KB: 2 bufs x {A[256][64], B[256][64]} bf16, XOR-swizzled
// (byte ^= (row&7)<<4, applied via pre-swizzled global src; linear DMA dest).
// Per K-tile, 4 phases: q(00) q(10) q(11) q(01); each phase stages one
// half-tile of tile t+1 (A-lo,B-lo,A-hi,B-hi) with 2 gload_lds/wave;
// counted vmcnt(2) at phases 1,2,4 (per-wave drain + barrier before any
// cross-wave read); never 0 in steady state. MODE 0: scatter QKV bf16.
// MODE 1: f32 row-major with phase factor.
template <int MODE>
__global__ __launch_bounds__(512, 2) void k_gemm8(const u16* __restrict__ A,
                                                  const u16* __restrict__ Bt,
                                                  void* __restrict__ outp,
                                                  const float* __restrict__ fac) {
  __shared__ __align__(16) char lds[131072];
  const int m0 = blockIdx.y * 256, n0 = blockIdx.x * 256;
  const int t = threadIdx.x;
  const int w = t >> 6, l = t & 63;
  const int wr = (w >> 2) * 128, wc = (w & 3) * 64;
  const int lr = l & 15, lq = l >> 4;
  const char* Ab = (const char*)A;
  const char* Bb = (const char*)Bt;

  f32x4 acc[8][4] = {};

  // stage one 16KB half (ISB: 0=A,1=B; H: 0=lo,1=hi) of K-tile TT into BUF
#define STAGE_HALF(MATB, R0, ISB, H, TT, BUF)                                     \
  {                                                                               \
    _Pragma("unroll") for (int j = 0; j < 2; j++) {                               \
      const int p = (j * 8 + w) * 1024 + l * 16;                                  \
      const int lg = p ^ (((p >> 7) & 7) << 4);                                   \
      async16(lds + (BUF) * 65536 + (ISB) * 32768 + (H) * 16384 + (j * 8 + w) * 1024, \
              (MATB) + (size_t)((R0) + (H) * 128 + (lg >> 7)) * 4096 + (TT) * 128 \
                  + (lg & 127));                                                  \
    }                                                                             \
  }

  // prologue: tile 0 -> buf 0 (order A-lo, B-lo, A-hi, B-hi)
  STAGE_HALF(Ab, m0, 0, 0, 0, 0);
  STAGE_HALF(Bb, n0, 1, 0, 0, 0);
  STAGE_HALF(Ab, m0, 0, 1, 0, 0);
  STAGE_HALF(Bb, n0, 1, 1, 0, 0);
  asm volatile("s_waitcnt vmcnt(2)" ::: "memory");
  __builtin_amdgcn_s_barrier();

  const int NT = D_DIM / 64;  // 32
  for (int tt = 0; tt < NT; tt++) {
    const int buf = tt & 1, nbuf = buf ^ 1;
    const bool pf = (tt + 1 < NT);
    const char* Ar = lds + buf * 65536;
    const char* Br = lds + buf * 65536 + 32768;
    short8 a0[4][2], a1[4][2], b0[2][2], b1[2][2];

    auto rdA = [&](short8 af[4][2], int mh) {
#pragma unroll
      for (int mi = 0; mi < 4; mi++)
#pragma unroll
        for (int ks = 0; ks < 2; ks++) {
          const int row = wr + mh * 64 + mi * 16 + lr;
          af[mi][ks] = *reinterpret_cast<const short8*>(
              Ar + ((row * 128 + ks * 64 + lq * 16) ^ ((row & 7) << 4)));
        }
    };
    auto rdB = [&](short8 bf[2][2], int nh) {
#pragma unroll
      for (int ni = 0; ni < 2; ni++)
#pragma unroll
        for (int ks = 0; ks < 2; ks++) {
          const int row = wc + nh * 32 + ni * 16 + lr;
          bf[ni][ks] = *reinterpret_cast<const short8*>(
              Br + ((row * 128 + ks * 64 + lq * 16) ^ ((row & 7) << 4)));
        }
    };

#define PHASE_MFMA(MH, NH, AF, BF)                                    \
  {                                                                   \
    asm volatile("" ::: "memory");                                    \
    __builtin_amdgcn_s_barrier();                                     \
    __builtin_amdgcn_s_setprio(1);                                    \
    _Pragma("unroll") for (int mi = 0; mi < 4; mi++)                  \
    _Pragma("unroll") for (int ni = 0; ni < 2; ni++)                  \
    _Pragma("unroll") for (int ks = 0; ks < 2; ks++)                  \
      acc[(MH) * 4 + mi][(NH) * 2 + ni] =                             \
          MFMA(AF[mi][ks], BF[ni][ks], acc[(MH) * 4 + mi][(NH) * 2 + ni]); \
    __builtin_amdgcn_s_setprio(0);                                    \
    asm volatile("" ::: "memory");                                    \
    __builtin_amdgcn_s_barrier();                                     \
  }

    // phase 1: q(0,0); stage A-lo(t+1)
    asm volatile("s_waitcnt vmcnt(2)" ::: "memory");
    rdA(a0, 0); rdB(b0, 0);
    if (pf) STAGE_HALF(Ab, m0, 0, 0, tt + 1, nbuf);
    PHASE_MFMA(0, 0, a0, b0);

    // phase 2: q(1,0); stage B-lo(t+1)
    if (pf) { asm volatile("s_waitcnt vmcnt(2)" ::: "memory"); }
    else    { asm volatile("s_waitcnt vmcnt(0)" ::: "memory"); }
    rdA(a1, 1);
    if (pf) STAGE_HALF(Bb, n0, 1, 0, tt + 1, nbuf);
    PHASE_MFMA(1, 0, a1, b0);

    // phase 3: q(1,1); stage A-hi(t+1)
    rdB(b1, 1);
    if (pf) STAGE_HALF(Ab, m0, 0, 1, tt + 1, nbuf);
    PHASE_MFMA(1, 1, a1, b1);

    // phase 4: q(0,1); stage B-hi(t+1)
    asm volatile("s_waitcnt vmcnt(2)" ::: "memory");
    rdA(a0, 0);
    if (pf) STAGE_HALF(Bb, n0, 1, 1, tt + 1, nbuf);
    PHASE_MFMA(0, 1, a0, b1);
  }
#undef STAGE_HALF
#undef PHASE_MFMA

  // epilogue
#pragma unroll
  for (int mi = 0; mi < 8; mi++) {
#pragma unroll
    for (int ni = 0; ni < 4; ni++) {
#pragma unroll
      for (int r = 0; r < 4; r++) {
        const int row = m0 + wr + mi * 16 + lq * 4 + r;
        const int col = n0 + wc + ni * 16 + lr;
        const float v = acc[mi][ni][r];
        if (MODE == 0) {
          const int mat = col >> 11;
          const int hh = (col >> 7) & 15;
          ((u16*)outp)[(size_t)mat * 8388608 +
                       (((size_t)((row >> 11) * NHEAD + hh)) * S_LEN + (row & 2047)) * HDIM +
                       (col & 127)] = f2bf(v);
        } else {
          ((float*)outp)[(size_t)row * D_DIM + col] = v * (1.0f + 0.1f * fac[row]);
        }
      }
    }
  }
}

// -------- phase projections pq/pk = x @ Wpq / x @ Wpk (f32) --------
__global__ __launch_bounds__(64) void k_phase_proj(const float* __restrict__ x,
                                                   const float* __restrict__ Wpq,
                                                   const float* __restrict__ Wpk,
                                                   float* __restrict__ pq,
                                                   float* __restrict__ pk) {
  int m = blockIdx.x;
  int l = threadIdx.x;
  int h = l & 15, part = l >> 4;
  const float* xr = x + (size_t)m * D_DIM + part * 512;
  float sq = 0.f, sk = 0.f;
  for (int k = 0; k < 512; k++) {
    float xv = xr[k];
    int kk = part * 512 + k;
    sq += xv * Wpq[(size_t)kk * NHEAD + h];
    sk += xv * Wpk[(size_t)kk * NHEAD + h];
  }
  sq += __shfl_xor(sq, 16); sq += __shfl_xor(sq, 32);
  sk += __shfl_xor(sk, 16); sk += __shfl_xor(sk, 32);
  if (l < 16) {
    pq[(size_t)m * NHEAD + l] = sq;
    pk[(size_t)m * NHEAD + l] = sk;
  }
}

__device__ __forceinline__ float wave_sum(float v) {
  v += __shfl_xor(v, 1);  v += __shfl_xor(v, 2);  v += __shfl_xor(v, 4);
  v += __shfl_xor(v, 8);  v += __shfl_xor(v, 16); v += __shfl_xor(v, 32);
  return v;
}

// -------- Ck/Sk = sum_s cos/sin(pk) per (b,h) --------
__global__ void k_phase_ck(const float* __restrict__ pk, float* __restrict__ Ck,
                           float* __restrict__ Sk) {
  int bh = blockIdx.x, b = bh >> 4, h = bh & 15;
  float c = 0.f, s = 0.f;
  for (int ss = threadIdx.x; ss < S_LEN; ss += 256) {
    float v = pk[((size_t)b * S_LEN + ss) * NHEAD + h];
    c += cosf(v); s += sinf(v);
  }
  c = wave_sum(c); s = wave_sum(s);
  __shared__ float rc[4], rs[4];
  int wv = threadIdx.x >> 6;
  if ((threadIdx.x & 63) == 0) { rc[wv] = c; rs[wv] = s; }
  __syncthreads();
  if (threadIdx.x == 0) {
    Ck[bh] = rc[0] + rc[1] + rc[2] + rc[3];
    Sk[bh] = rs[0] + rs[1] + rs[2] + rs[3];
  }
}

// -------- phase_mod[m] --------
__global__ void k_phase_mod(const float* __restrict__ pq, const float* __restrict__ Ck,
                            const float* __restrict__ Sk, float* __restrict__ pm) {
  int m = blockIdx.x * 256 + threadIdx.x;
  int b = m >> 11;
  float a = 0.f;
#pragma unroll
  for (int h = 0; h < NHEAD; h++) {
    float v = pq[(size_t)m * NHEAD + h];
    a += cosf(v) * Ck[b * NHEAD + h] + sinf(v) * Sk[b * NHEAD + h];
  }
  pm[m] = a * (1.0f / (S_LEN * NHEAD));
}

// -------- causal flash attention: 4 warps x 32 q-rows, LDS-staged K/V --------
__global__ __launch_bounds__(256, 2) void k_attn(const u16* __restrict__ Q,
                                                 const u16* __restrict__ K,
                                                 const u16* __restrict__ Vt,
                                                 u16* __restrict__ ctx) {
  const int bh = blockIdx.x;
  const int gy = blockIdx.y;
  const int g = (gy < 8) ? (15 - gy) : (gy - 8);  // pair long/short across dispatch
  const int b = bh >> 4, h = bh & 15;
  const int t = threadIdx.x;
  const int w = t >> 6, l = t & 63;
  const int ln = l & 31, hi = l >> 5;
  const int q0w = g * 128 + w * 32;
  const int qq = q0w + ln;
  const float scale = 0.08838834764831845f;

  const u16* Qp = Q + (size_t)bh * S_LEN * HDIM;
  const char* Kg = (const char*)(K + (size_t)bh * S_LEN * HDIM);
  const char* Vg = (const char*)(Vt + (size_t)bh * HDIM * S_LEN);

  __shared__ __align__(16) char Ks[16384];
  __shared__ __align__(16) char Vs[16384];

  short8 qf[8];
#pragma unroll
  for (int c = 0; c < 8; c++)
    qf[c] = *reinterpret_cast<const short8*>(Qp + (size_t)qq * HDIM + c * 16 + hi * 8);

  f32x16 o[4];
#pragma unroll
  for (int ds = 0; ds < 4; ds++)
#pragma unroll
    for (int r = 0; r < 16; r++) o[ds][r] = 0.f;
  float mrun = -1e30f, lsum = 0.f;

  const int kend = (g + 1) * 128;
  for (int k0 = 0; k0 < kend; k0 += 64) {
#pragma unroll
    for (int i = 0; i < 4; i++) {
      const int key = i * 16 + w * 4 + (l >> 4);
      async16(Ks + i * 4096 + w * 1024,
              Kg + (size_t)(k0 + key) * 256 + (((l & 15) * 16) ^ ((key & 7) << 4)));
      const int d = i * 32 + w * 8 + (l >> 3);
      async16(Vs + i * 4096 + w * 1024,
              Vg + (size_t)d * (S_LEN * 2) + k0 * 2 + (((l & 7) * 16) ^ ((d & 7) << 4)));
    }
    __syncthreads();
    if (k0 < q0w + 32) {
      f32x16 s[2];
#pragma unroll
      for (int ks = 0; ks < 2; ks++)
#pragma unroll
        for (int r = 0; r < 16; r++) s[ks][r] = 0.f;
      __builtin_amdgcn_s_setprio(1);
#pragma unroll
      for (int ks = 0; ks < 2; ks++) {
        const int key = ks * 32 + ln;
        const char* kb = Ks + key * 256;
        const unsigned swzk = (unsigned)((key & 7) << 4);
#pragma unroll
        for (int c = 0; c < 8; c++) {
          const short8 kf = *reinterpret_cast<const short8*>(
              kb + (((unsigned)(c * 32 + hi * 16)) ^ swzk));
          s[ks] = MFMA32(kf, qf[c], s[ks]);
        }
      }
      __builtin_amdgcn_s_setprio(0);
      float p[32];
      float mx = -1e30f;
#pragma unroll
      for (int ks = 0; ks < 2; ks++)
#pragma unroll
        for (int r = 0; r < 16; r++) {
          const int key = k0 + ks * 32 + (r & 3) + 8 * (r >> 2) + 4 * hi;
          const float v = (key <= qq) ? s[ks][r] * scale : -1e30f;
          p[ks * 16 + r] = v;
          mx = fmaxf(mx, v);
        }
      mx = fmaxf(mx, __shfl_xor(mx, 32));
      const float nm = fmaxf(mrun, mx);
      const float f = __expf(mrun - nm);
      float rs = 0.f;
#pragma unroll
      for (int i = 0; i < 32; i++) { p[i] = __expf(p[i] - nm); rs += p[i]; }
      rs += __shfl_xor(rs, 32);
      lsum = lsum * f + rs;
      mrun = nm;
#pragma unroll
      for (int ds = 0; ds < 4; ds++)
#pragma unroll
        for (int r = 0; r < 16; r++) o[ds][r] *= f;
      short8 bfr[4];
#pragma unroll
      for (int sub = 0; sub < 2; sub++) {
#pragma unroll
        for (int half = 0; half < 2; half++) {
          const int pb = sub * 16 + half * 8;
          unsigned X1 = cvtpk(p[pb + 0], p[pb + 1]);
          unsigned X2 = cvtpk(p[pb + 2], p[pb + 3]);
          unsigned Y1 = cvtpk(p[pb + 4], p[pb + 5]);
          unsigned Y2 = cvtpk(p[pb + 6], p[pb + 7]);
          plswap(X1, Y1);
          plswap(X2, Y2);
          i32x4 bw;
          bw[0] = (int)X1; bw[1] = (int)X2; bw[2] = (int)Y1; bw[3] = (int)Y2;
          bfr[sub * 2 + half] = __builtin_bit_cast(short8, bw);
        }
      }
      __builtin_amdgcn_s_setprio(1);
#pragma unroll
      for (int ds = 0; ds < 4; ds++) {
        const int d = ds * 32 + ln;
        const char* vb = Vs + d * 128;
        const unsigned swzv = (unsigned)((d & 7) << 4);
#pragma unroll
        for (int slot = 0; slot < 4; slot++) {
          const short8 vf = *reinterpret_cast<const short8*>(
              vb + (((unsigned)(slot * 32 + hi * 16)) ^ swzv));
          o[ds] = MFMA32(vf, bfr[slot], o[ds]);
        }
      }
      __builtin_amdgcn_s_setprio(0);
    }
    __syncthreads();
  }

  const float rl = 1.0f / lsum;
#pragma unroll
  for (int ds = 0; ds < 4; ds++) {
#pragma unroll
    for (int rq = 0; rq < 4; rq++) {
      const int d = ds * 32 + 8 * rq + 4 * hi;
      ushort4 pk4;
      pk4.x = f2bf(o[ds][rq * 4 + 0] * rl);
      pk4.y = f2bf(o[ds][rq * 4 + 1] * rl);
      pk4.z = f2bf(o[ds][rq * 4 + 2] * rl);
      pk4.w = f2bf(o[ds][rq * 4 + 3] * rl);
      *reinterpret_cast<ushort4*>(ctx + ((size_t)(b * S_LEN + qq)) * D_DIM + h * HDIM + d) = pk4;
    }
  }
}

extern "C" void kernel_launch(void* const* d_in, const int* in_sizes, int n_in,
                              void* d_out, int out_size, void* d_ws, size_t ws_size,
                              hipStream_t stream) {
  const float* x   = (const float*)d_in[0];
  const float* Wq  = (const float*)d_in[1];
  const float* Wk  = (const float*)d_in[2];
  const float* Wv  = (const float*)d_in[3];
  const float* Wo  = (const float*)d_in[4];
  const float* Wpq = (const float*)d_in[5];
  const float* Wpk = (const float*)d_in[6];

  char* ws = (char*)d_ws;
  u16* xb   = (u16*)(ws + 0);            // 16 MB  x bf16 [4096][2048]
  u16* Wqt  = (u16*)(ws + 16777216);     // 8 MB each, transposed bf16 (Wq,Wk,Wv contiguous)
  u16* Wkt  = (u16*)(ws + 25165824);
  u16* Wvt  = (u16*)(ws + 33554432);
  u16* Wot  = (u16*)(ws + 41943040);
  u16* Qb   = (u16*)(ws + 50331648);     // [b,h,s,d] bf16 (Q,K,V contiguous)
  u16* Kb   = (u16*)(ws + 67108864);
  u16* Vb   = (u16*)(ws + 83886080);     // V, later reused as ctx
  u16* Vt   = (u16*)(ws + 100663296);    // [b,h,d,s] bf16
  float* pq = (float*)(ws + 117440512);
  float* pk = (float*)(ws + 117702656);
  float* Ck = (float*)(ws + 117964800);
  float* Sk = (float*)(ws + 117964928);
  float* pm = (float*)(ws + 117965056);

  k_cvt_x<<<dim3(M_ROWS * D_DIM / 1024), 256, 0, stream>>>(x, xb);
  k_cvt_wt<<<dim3(64, 64), 256, 0, stream>>>(Wq, Wqt);
  k_cvt_wt<<<dim3(64, 64), 256, 0, stream>>>(Wk, Wkt);
  k_cvt_wt<<<dim3(64, 64), 256, 0, stream>>>(Wv, Wvt);
  k_cvt_wt<<<dim3(64, 64), 256, 0, stream>>>(Wo, Wot);

  // fused QKV projection: Bt = [Wqt;Wkt;Wvt] = [6144][2048]
  k_gemm8<0><<<dim3(24, 16), 512, 0, stream>>>(xb, Wqt, Qb, nullptr);

  k_vtrans<<<dim3(64, 4, 32), 256, 0, stream>>>(Vb, Vt);

  k_phase_proj<<<dim3(M_ROWS), 64, 0, stream>>>(x, Wpq, Wpk, pq, pk);
  k_phase_ck<<<dim3(32), 256, 0, stream>>>(pk, Ck, Sk);
  k_phase_mod<<<dim3(16), 256, 0, stream>>>(pq, Ck, Sk, pm);

  k_attn<<<dim3(32, 16), 256, 0, stream>>>(Qb, Kb, Vt, Vb /*ctx*/);

  k_gemm8<1><<<dim3(8, 16), 512, 0, stream>>>(Vb /*ctx*/, Wot, (void*)d_out, pm);
}

// Round 6
// 327.418 us; speedup vs baseline: 2.7543x; 1.0716x over previous
//
#include <hip/hip_runtime.h>
#include <hip/hip_bf16.h>

typedef __attribute__((ext_vector_type(8))) short short8;
typedef __attribute__((ext_vector_type(4))) float f32x4;
typedef __attribute__((ext_vector_type(16))) float f32x16;
typedef __attribute__((ext_vector_type(4))) int i32x4;
typedef unsigned short u16;

#define S_LEN 2048
#define D_DIM 2048
#define NHEAD 16
#define HDIM 128
#define M_ROWS 4096

#define MFMA(a,b,c) __builtin_amdgcn_mfma_f32_16x16x32_bf16(a,b,c,0,0,0)
#define MFMA32(a,b,c) __builtin_amdgcn_mfma_f32_32x32x16_bf16(a,b,c,0,0,0)

__device__ __forceinline__ u16 f2bf(float f) {
  union { float f; unsigned u; } v; v.f = f;
  unsigned r = v.u + 0x7fffu + ((v.u >> 16) & 1u);
  return (u16)(r >> 16);
}

__device__ __forceinline__ void async16(void* lds, const void* g) {
  __builtin_amdgcn_global_load_lds(
      (const __attribute__((address_space(1))) unsigned*)g,
      (__attribute__((address_space(3))) unsigned*)lds, 16, 0, 0);
}

__device__ __forceinline__ unsigned cvtpk(float lo, float hi) {
  unsigned r;
  asm("v_cvt_pk_bf16_f32 %0, %1, %2" : "=v"(r) : "v"(lo), "v"(hi));
  return r;
}
__device__ __forceinline__ void plswap(unsigned& x, unsigned& y) {
  asm("v_permlane32_swap_b32 %0, %1" : "+v"(x), "+v"(y));
}

// ---------------- x -> bf16 ----------------
__global__ void k_cvt_x(const float* __restrict__ x, u16* __restrict__ xb) {
  int i = blockIdx.x * 256 + threadIdx.x;
  float4 v = reinterpret_cast<const float4*>(x)[i];
  ushort4 o;
  o.x = f2bf(v.x); o.y = f2bf(v.y); o.z = f2bf(v.z); o.w = f2bf(v.w);
  reinterpret_cast<ushort4*>(xb)[i] = o;
}

// -------- W[k][n] f32 -> Wt[n][k] bf16 (transpose+convert) --------
__global__ void k_cvt_wt(const float* __restrict__ W, u16* __restrict__ Wt) {
  __shared__ u16 tile[32][33];
  int n0 = blockIdx.x * 32, k0 = blockIdx.y * 32;
  int tx = threadIdx.x & 31, ty = threadIdx.x >> 5;
#pragma unroll
  for (int i = 0; i < 4; i++)
    tile[ty + i * 8][tx] = f2bf(W[(size_t)(k0 + ty + i * 8) * D_DIM + n0 + tx]);
  __syncthreads();
#pragma unroll
  for (int i = 0; i < 4; i++)
    Wt[(size_t)(n0 + ty + i * 8) * D_DIM + k0 + tx] = tile[tx][ty + i * 8];
}

// -------- V[b,h,s,d] -> Vt[b,h,d,s] (bf16 transpose) --------
__global__ void k_vtrans(const u16* __restrict__ V, u16* __restrict__ Vt) {
  __shared__ u16 tile[32][33];
  int s0 = blockIdx.x * 32, d0 = blockIdx.y * 32, bh = blockIdx.z;
  const u16* Vp = V + (size_t)bh * S_LEN * HDIM;
  u16* Vtp = Vt + (size_t)bh * HDIM * S_LEN;
  int tx = threadIdx.x & 31, ty = threadIdx.x >> 5;
#pragma unroll
  for (int i = 0; i < 4; i++)
    tile[ty + i * 8][tx] = Vp[(size_t)(s0 + ty + i * 8) * HDIM + d0 + tx];
  __syncthreads();
#pragma unroll
  for (int i = 0; i < 4; i++)
    Vtp[(size_t)(d0 + ty + i * 8) * S_LEN + s0 + tx] = tile[tx][ty + i * 8];
}

// ======== 2-phase K-split counted GEMM: C = A[M][K] * Bt[N][K]^T ========
// Tile 256 x BN (BN = NFRAG*64), BK=64 split into 2 K-subs of 32.
// Unit U(t,s) = {A-sub, B-sub} staged cooperatively; per-wave LPU loads/unit,
// identical issue order across waves -> vmcnt(LPU)+barrier guarantees all
// units except the newest are fully LDS-resident for ALL waves (race-free).
// Phase s of tile t: vmcnt(LPU); barrier; stage U(t+1,s) -> nbuf; ds_read
// sub s; 8*NFRAG MFMA (K=32). vmcnt(0) only at the last phase.
// LDS rows are 64B (4 x 16B slots); swizzle slot ^= (row>>1)&3 applied via
// pre-swizzled global source + same XOR on ds_read (involution, rule 21).
template <int NFRAG, int MODE>
__global__ __launch_bounds__(512, 2) void k_gemm2p(const u16* __restrict__ A,
                                                   const u16* __restrict__ Bt,
                                                   void* __restrict__ outp,
                                                   const float* __restrict__ fac) {
  constexpr int BN = NFRAG * 64;
  constexpr int ASUB = 16384;        // 256 rows * 64B
  constexpr int BSUB = BN * 64;
  constexpr int BBASE = 4 * ASUB;
  constexpr int LPU = 2 + NFRAG / 2; // loads per unit per wave
  __shared__ __align__(16) char lds[4 * ASUB + 4 * BSUB];
  const int m0 = blockIdx.y * 256, n0 = blockIdx.x * BN;
  const int t = threadIdx.x;
  const int w = t >> 6, l = t & 63;
  const int wr = (w >> 2) * 128, wc = (w & 3) * (BN / 4);
  const int lr = l & 15, lq = l >> 4;
  const char* Ab = (const char*)A;
  const char* Bb = (const char*)Bt;

  f32x4 acc[8][NFRAG] = {};

  auto stage_unit = [&](int tt, int s, int buf) {
#pragma unroll
    for (int j = 0; j < 2; j++) {  // A-sub: 16KB = 2 x 8KB issues
      const int p = j * 8192 + w * 1024 + l * 16;
      const int row = p >> 6, slot = (p >> 4) & 3;
      async16(lds + buf * 2 * ASUB + s * ASUB + j * 8192 + w * 1024,
              Ab + (size_t)(m0 + row) * 4096 + tt * 128 + s * 64 +
                  ((slot ^ ((row >> 1) & 3)) * 16));
    }
#pragma unroll
    for (int j = 0; j < NFRAG / 2; j++) {  // B-sub
      const int p = j * 8192 + w * 1024 + l * 16;
      const int row = p >> 6, slot = (p >> 4) & 3;
      async16(lds + BBASE + buf * 2 * BSUB + s * BSUB + j * 8192 + w * 1024,
              Bb + (size_t)(n0 + row) * 4096 + tt * 128 + s * 64 +
                  ((slot ^ ((row >> 1) & 3)) * 16));
    }
  };

  auto phase = [&](int buf, int s) {
    const char* Ar = lds + buf * 2 * ASUB + s * ASUB;
    const char* Br = lds + BBASE + buf * 2 * BSUB + s * BSUB;
    short8 af[8], bf[NFRAG];
#pragma unroll
    for (int mi = 0; mi < 8; mi++) {
      const int row = wr + mi * 16 + lr;
      af[mi] = *reinterpret_cast<const short8*>(
          Ar + row * 64 + ((lq ^ ((row >> 1) & 3)) * 16));
    }
#pragma unroll
    for (int ni = 0; ni < NFRAG; ni++) {
      const int row = wc + ni * 16 + lr;
      bf[ni] = *reinterpret_cast<const short8*>(
          Br + row * 64 + ((lq ^ ((row >> 1) & 3)) * 16));
    }
    __builtin_amdgcn_s_setprio(1);
#pragma unroll
    for (int mi = 0; mi < 8; mi++)
#pragma unroll
      for (int ni = 0; ni < NFRAG; ni++)
        acc[mi][ni] = MFMA(af[mi], bf[ni], acc[mi][ni]);
    __builtin_amdgcn_s_setprio(0);
  };

  // prologue: tile 0 both subs -> buf 0
  stage_unit(0, 0, 0);
  stage_unit(0, 1, 0);

  const int NT = D_DIM / 64;  // 32
  for (int tt = 0; tt < NT; tt++) {
    const int buf = tt & 1;
    const bool pf = (tt + 1 < NT);
    // phase 0: need U(t,0); newest-LPU = U(t,1) -> vmcnt(LPU) always safe
    asm volatile("s_waitcnt vmcnt(%0)" :: "n"(LPU) : "memory");
    __builtin_amdgcn_s_barrier();
    asm volatile("" ::: "memory");
    if (pf) stage_unit(tt + 1, 0, buf ^ 1);
    phase(buf, 0);
    // phase 1: need U(t,1); newest-LPU = U(t+1,0) if staged, else drain
    if (pf) asm volatile("s_waitcnt vmcnt(%0)" :: "n"(LPU) : "memory");
    else    asm volatile("s_waitcnt vmcnt(0)" ::: "memory");
    __builtin_amdgcn_s_barrier();
    asm volatile("" ::: "memory");
    if (pf) stage_unit(tt + 1, 1, buf ^ 1);
    phase(buf, 1);
  }

  // epilogue
#pragma unroll
  for (int mi = 0; mi < 8; mi++) {
#pragma unroll
    for (int ni = 0; ni < NFRAG; ni++) {
#pragma unroll
      for (int r = 0; r < 4; r++) {
        const int row = m0 + wr + mi * 16 + lq * 4 + r;
        const int col = n0 + wc + ni * 16 + lr;
        const float v = acc[mi][ni][r];
        if (MODE == 0) {
          const int mat = col >> 11;
          const int hh = (col >> 7) & 15;
          ((u16*)outp)[(size_t)mat * 8388608 +
                       (((size_t)((row >> 11) * NHEAD + hh)) * S_LEN + (row & 2047)) * HDIM +
                       (col & 127)] = f2bf(v);
        } else {
          ((float*)outp)[(size_t)row * D_DIM + col] = v * (1.0f + 0.1f * fac[row]);
        }
      }
    }
  }
}

// -------- phase projections pq/pk = x @ Wpq / x @ Wpk (f32) --------
__global__ __launch_bounds__(64) void k_phase_proj(const float* __restrict__ x,
                                                   const float* __restrict__ Wpq,
                                                   const float* __restrict__ Wpk,
                                                   float* __restrict__ pq,
                                                   float* __restrict__ pk) {
  int m = blockIdx.x;
  int l = threadIdx.x;
  int h = l & 15, part = l >> 4;
  const float* xr = x + (size_t)m * D_DIM + part * 512;
  float sq = 0.f, sk = 0.f;
  for (int k = 0; k < 512; k++) {
    float xv = xr[k];
    int kk = part * 512 + k;
    sq += xv * Wpq[(size_t)kk * NHEAD + h];
    sk += xv * Wpk[(size_t)kk * NHEAD + h];
  }
  sq += __shfl_xor(sq, 16); sq += __shfl_xor(sq, 32);
  sk += __shfl_xor(sk, 16); sk += __shfl_xor(sk, 32);
  if (l < 16) {
    pq[(size_t)m * NHEAD + l] = sq;
    pk[(size_t)m * NHEAD + l] = sk;
  }
}

__device__ __forceinline__ float wave_sum(float v) {
  v += __shfl_xor(v, 1);  v += __shfl_xor(v, 2);  v += __shfl_xor(v, 4);
  v += __shfl_xor(v, 8);  v += __shfl_xor(v, 16); v += __shfl_xor(v, 32);
  return v;
}

// -------- Ck/Sk = sum_s cos/sin(pk) per (b,h) --------
__global__ void k_phase_ck(const float* __restrict__ pk, float* __restrict__ Ck,
                           float* __restrict__ Sk) {
  int bh = blockIdx.x, b = bh >> 4, h = bh & 15;
  float c = 0.f, s = 0.f;
  for (int ss = threadIdx.x; ss < S_LEN; ss += 256) {
    float v = pk[((size_t)b * S_LEN + ss) * NHEAD + h];
    c += cosf(v); s += sinf(v);
  }
  c = wave_sum(c); s = wave_sum(s);
  __shared__ float rc[4], rs[4];
  int wv = threadIdx.x >> 6;
  if ((threadIdx.x & 63) == 0) { rc[wv] = c; rs[wv] = s; }
  __syncthreads();
  if (threadIdx.x == 0) {
    Ck[bh] = rc[0] + rc[1] + rc[2] + rc[3];
    Sk[bh] = rs[0] + rs[1] + rs[2] + rs[3];
  }
}

// -------- phase_mod[m] --------
__global__ void k_phase_mod(const float* __restrict__ pq, const float* __restrict__ Ck,
                            const float* __restrict__ Sk, float* __restrict__ pm) {
  int m = blockIdx.x * 256 + threadIdx.x;
  int b = m >> 11;
  float a = 0.f;
#pragma unroll
  for (int h = 0; h < NHEAD; h++) {
    float v = pq[(size_t)m * NHEAD + h];
    a += cosf(v) * Ck[b * NHEAD + h] + sinf(v) * Sk[b * NHEAD + h];
  }
  pm[m] = a * (1.0f / (S_LEN * NHEAD));
}

// -------- causal flash attention: 4 warps x 32 q-rows, LDS-staged K/V --------
__global__ __launch_bounds__(256, 2) void k_attn(const u16* __restrict__ Q,
                                                 const u16* __restrict__ K,
                                                 const u16* __restrict__ Vt,
                                                 u16* __restrict__ ctx) {
  const int bh = blockIdx.x;
  const int gy = blockIdx.y;
  const int g = (gy < 8) ? (15 - gy) : (gy - 8);  // pair long/short across dispatch
  const int b = bh >> 4, h = bh & 15;
  const int t = threadIdx.x;
  const int w = t >> 6, l = t & 63;
  const int ln = l & 31, hi = l >> 5;
  const int q0w = g * 128 + w * 32;
  const int qq = q0w + ln;
  const float scale = 0.08838834764831845f;

  const u16* Qp = Q + (size_t)bh * S_LEN * HDIM;
  const char* Kg = (const char*)(K + (size_t)bh * S_LEN * HDIM);
  const char* Vg = (const char*)(Vt + (size_t)bh * HDIM * S_LEN);

  __shared__ __align__(16) char Ks[16384];
  __shared__ __align__(16) char Vs[16384];

  short8 qf[8];
#pragma unroll
  for (int c = 0; c < 8; c++)
    qf[c] = *reinterpret_cast<const short8*>(Qp + (size_t)qq * HDIM + c * 16 + hi * 8);

  f32x16 o[4];
#pragma unroll
  for (int ds = 0; ds < 4; ds++)
#pragma unroll
    for (int r = 0; r < 16; r++) o[ds][r] = 0.f;
  float mrun = -1e30f, lsum = 0.f;

  const int kend = (g + 1) * 128;
  for (int k0 = 0; k0 < kend; k0 += 64) {
#pragma unroll
    for (int i = 0; i < 4; i++) {
      const int key = i * 16 + w * 4 + (l >> 4);
      async16(Ks + i * 4096 + w * 1024,
              Kg + (size_t)(k0 + key) * 256 + (((l & 15) * 16) ^ ((key & 15) << 4)));
      const int d = i * 32 + w * 8 + (l >> 3);
      async16(Vs + i * 4096 + w * 1024,
              Vg + (size_t)d * (S_LEN * 2) + k0 * 2 + (((l & 7) * 16) ^ ((d & 7) << 4)));
    }
    __syncthreads();
    if (k0 < q0w + 32) {
      f32x16 s[2];
#pragma unroll
      for (int ks = 0; ks < 2; ks++)
#pragma unroll
        for (int r = 0; r < 16; r++) s[ks][r] = 0.f;
      __builtin_amdgcn_s_setprio(1);
#pragma unroll
      for (int ks = 0; ks < 2; ks++) {
        const int key = ks * 32 + ln;
        const char* kb = Ks + key * 256;
        const unsigned swzk = (unsigned)((key & 15) << 4);
#pragma unroll
        for (int c = 0; c < 8; c++) {
          const short8 kf = *reinterpret_cast<const short8*>(
              kb + (((unsigned)(c * 32 + hi * 16)) ^ swzk));
          s[ks] = MFMA32(kf, qf[c], s[ks]);
        }
      }
      __builtin_amdgcn_s_setprio(0);
      float p[32];
      float mx = -1e30f;
#pragma unroll
      for (int ks = 0; ks < 2; ks++)
#pragma unroll
        for (int r = 0; r < 16; r++) {
          const int key = k0 + ks * 32 + (r & 3) + 8 * (r >> 2) + 4 * hi;
          const float v = (key <= qq) ? s[ks][r] * scale : -1e30f;
          p[ks * 16 + r] = v;
          mx = fmaxf(mx, v);
        }
      mx = fmaxf(mx, __shfl_xor(mx, 32));
      const float nm = fmaxf(mrun, mx);
      const float f = __expf(mrun - nm);
      float rs = 0.f;
#pragma unroll
      for (int i = 0; i < 32; i++) { p[i] = __expf(p[i] - nm); rs += p[i]; }
      rs += __shfl_xor(rs, 32);
      lsum = lsum * f + rs;
      mrun = nm;
#pragma unroll
      for (int ds = 0; ds < 4; ds++)
#pragma unroll
        for (int r = 0; r < 16; r++) o[ds][r] *= f;
      short8 bfr[4];
#pragma unroll
      for (int sub = 0; sub < 2; sub++) {
#pragma unroll
        for (int half = 0; half < 2; half++) {
          const int pb = sub * 16 + half * 8;
          unsigned X1 = cvtpk(p[pb + 0], p[pb + 1]);
          unsigned X2 = cvtpk(p[pb + 2], p[pb + 3]);
          unsigned Y1 = cvtpk(p[pb + 4], p[pb + 5]);
          unsigned Y2 = cvtpk(p[pb + 6], p[pb + 7]);
          plswap(X1, Y1);
          plswap(X2, Y2);
          i32x4 bw;
          bw[0] = (int)X1; bw[1] = (int)X2; bw[2] = (int)Y1; bw[3] = (int)Y2;
          bfr[sub * 2 + half] = __builtin_bit_cast(short8, bw);
        }
      }
      __builtin_amdgcn_s_setprio(1);
#pragma unroll
      for (int ds = 0; ds < 4; ds++) {
        const int d = ds * 32 + ln;
        const char* vb = Vs + d * 128;
        const unsigned swzv = (unsigned)((d & 7) << 4);
#pragma unroll
        for (int slot = 0; slot < 4; slot++) {
          const short8 vf = *reinterpret_cast<const short8*>(
              vb + (((unsigned)(slot * 32 + hi * 16)) ^ swzv));
          o[ds] = MFMA32(vf, bfr[slot], o[ds]);
        }
      }
      __builtin_amdgcn_s_setprio(0);
    }
    __syncthreads();
  }

  const float rl = 1.0f / lsum;
#pragma unroll
  for (int ds = 0; ds < 4; ds++) {
#pragma unroll
    for (int rq = 0; rq < 4; rq++) {
      const int d = ds * 32 + 8 * rq + 4 * hi;
      ushort4 pk4;
      pk4.x = f2bf(o[ds][rq * 4 + 0] * rl);
      pk4.y = f2bf(o[ds][rq * 4 + 1] * rl);
      pk4.z = f2bf(o[ds][rq * 4 + 2] * rl);
      pk4.w = f2bf(o[ds][rq * 4 + 3] * rl);
      *reinterpret_cast<ushort4*>(ctx + ((size_t)(b * S_LEN + qq)) * D_DIM + h * HDIM + d) = pk4;
    }
  }
}

extern "C" void kernel_launch(void* const* d_in, const int* in_sizes, int n_in,
                              void* d_out, int out_size, void* d_ws, size_t ws_size,
                              hipStream_t stream) {
  const float* x   = (const float*)d_in[0];
  const float* Wq  = (const float*)d_in[1];
  const float* Wk  = (const float*)d_in[2];
  const float* Wv  = (const float*)d_in[3];
  const float* Wo  = (const float*)d_in[4];
  const float* Wpq = (const float*)d_in[5];
  const float* Wpk = (const float*)d_in[6];

  char* ws = (char*)d_ws;
  u16* xb   = (u16*)(ws + 0);            // 16 MB  x bf16 [4096][2048]
  u16* Wqt  = (u16*)(ws + 16777216);     // 8 MB each, transposed bf16 (Wq,Wk,Wv contiguous)
  u16* Wkt  = (u16*)(ws + 25165824);
  u16* Wvt  = (u16*)(ws + 33554432);
  u16* Wot  = (u16*)(ws + 41943040);
  u16* Qb   = (u16*)(ws + 50331648);     // [b,h,s,d] bf16 (Q,K,V contiguous)
  u16* Kb   = (u16*)(ws + 67108864);
  u16* Vb   = (u16*)(ws + 83886080);     // V, later reused as ctx
  u16* Vt   = (u16*)(ws + 100663296);    // [b,h,d,s] bf16
  float* pq = (float*)(ws + 117440512);
  float* pk = (float*)(ws + 117702656);
  float* Ck = (float*)(ws + 117964800);
  float* Sk = (float*)(ws + 117964928);
  float* pm = (float*)(ws + 117965056);

  k_cvt_x<<<dim3(M_ROWS * D_DIM / 1024), 256, 0, stream>>>(x, xb);
  k_cvt_wt<<<dim3(64, 64), 256, 0, stream>>>(Wq, Wqt);
  k_cvt_wt<<<dim3(64, 64), 256, 0, stream>>>(Wk, Wkt);
  k_cvt_wt<<<dim3(64, 64), 256, 0, stream>>>(Wv, Wvt);
  k_cvt_wt<<<dim3(64, 64), 256, 0, stream>>>(Wo, Wot);

  // fused QKV projection: Bt = [Wqt;Wkt;Wvt] = [6144][2048], 256x256 tiles
  k_gemm2p<4, 0><<<dim3(24, 16), 512, 0, stream>>>(xb, Wqt, Qb, nullptr);

  k_vtrans<<<dim3(64, 4, 32), 256, 0, stream>>>(Vb, Vt);

  k_phase_proj<<<dim3(M_ROWS), 64, 0, stream>>>(x, Wpq, Wpk, pq, pk);
  k_phase_ck<<<dim3(32), 256, 0, stream>>>(pk, Ck, Sk);
  k_phase_mod<<<dim3(16), 256, 0, stream>>>(pq, Ck, Sk, pm);

  k_attn<<<dim3(32, 16), 256, 0, stream>>>(Qb, Kb, Vt, Vb /*ctx*/);

  // O-proj: 256x128 tiles -> grid 16x16 = 256 blocks (all CUs busy)
  k_gemm2p<2, 1><<<dim3(16, 16), 512, 0, stream>>>(Vb /*ctx*/, Wot, (void*)d_out, pm);
}